// Round 3
// baseline (282.476 us; speedup 1.0000x reference)
//
#include <hip/hip_runtime.h>
#include <hip/hip_fp16.h>
#include <cmath>

#define NRAYS 4096
#define NSAMP 256

// fp16 workspace layout (offsets in __half units):
//   dpt[i][y][x][16]  3*65536*16 = 3145728
//   apt[i][y][x][32]  3*65536*32 = 6291456   (ch 24..31 zero pad)
//   dlt[i][l][16]     3*256*16   = 12288
//   alt[i][l][32]     3*256*32   = 24576     (pad)
static constexpr int DPT_H = 0;
static constexpr int APT_H = 3145728;
static constexpr int DLT_H = APT_H + 6291456;   // 9437184
static constexpr int ALT_H = DLT_H + 12288;     // 9449472
static constexpr int WS_HALVES = ALT_H + 24576; // 9474048 (~18.1 MB)
static constexpr size_t WS_NEED = (size_t)WS_HALVES * sizeof(__half);

__device__ __forceinline__ float4 ld4(const float* p) { return *(const float4*)p; }

__device__ __forceinline__ float4 lerp4(float4 a, float4 b, float w) {
  float4 o;
  o.x = fmaf(w, b.x - a.x, a.x);
  o.y = fmaf(w, b.y - a.y, a.y);
  o.z = fmaf(w, b.z - a.z, a.z);
  o.w = fmaf(w, b.w - a.w, a.w);
  return o;
}

__device__ __forceinline__ float4 mul4(float4 a, float4 b) {
  float4 o; o.x = a.x*b.x; o.y = a.y*b.y; o.z = a.z*b.z; o.w = a.w*b.w; return o;
}

__device__ __forceinline__ float dot4(float4 a, float4 b) {
  return a.x * b.x + a.y * b.y + a.z * b.z + a.w * b.w;
}

// align_corners=True grid coord -> (i0, frac). N=256 fixed.
__device__ __forceinline__ void grid_uv(float c, int& i0, float& w) {
  float f = (c + 1.0f) * 127.5f;
  float fl = floorf(f);
  fl = fminf(fmaxf(fl, 0.0f), 254.0f);
  i0 = (int)fl;
  w = f - fl;
}

// 8-byte load of 4 halves -> float4
__device__ __forceinline__ float4 load4h(const __half* p) {
  uint2 raw = *(const uint2*)p;
  float2 f0 = __half22float2(__builtin_bit_cast(__half2, raw.x));
  float2 f1 = __half22float2(__builtin_bit_cast(__half2, raw.y));
  return make_float4(f0.x, f0.y, f1.x, f1.y);
}

// 16-byte load of 8 halves -> 2x float4
__device__ __forceinline__ void load8h(const __half* p, float4& lo, float4& hi) {
  uint4 raw = *(const uint4*)p;
  float2 f0 = __half22float2(__builtin_bit_cast(__half2, raw.x));
  float2 f1 = __half22float2(__builtin_bit_cast(__half2, raw.y));
  float2 f2 = __half22float2(__builtin_bit_cast(__half2, raw.z));
  float2 f3 = __half22float2(__builtin_bit_cast(__half2, raw.w));
  lo = make_float4(f0.x, f0.y, f1.x, f1.y);
  hi = make_float4(f2.x, f2.y, f3.x, f3.y);
}

__device__ __forceinline__ unsigned pack2h(float a, float b) {
  return __builtin_bit_cast(unsigned, __floats2half2_rn(a, b));
}

// ---------------------------------------------------------------------------
// Transpose fp32 [c][y][x] -> fp16 channel-innermost. One thread = 8 output
// halves (16B store, fully coalesced).
// ---------------------------------------------------------------------------
__global__ __launch_bounds__(256) void transpose_h_kernel(
    const float* __restrict__ dp, const float* __restrict__ dl,
    const float* __restrict__ ap, const float* __restrict__ al,
    __half* __restrict__ ws) {
  constexpr int DPn = 3 * 65536 * 2;  // 393216
  constexpr int APn = 3 * 65536 * 4;  // 786432
  constexpr int DLn = 3 * 256 * 2;    // 1536
  constexpr int ALn = 3 * 256 * 4;    // 3072
  constexpr int TOT = DPn + APn + DLn + ALn;  // 1184256
  int idx = blockIdx.x * 256 + threadIdx.x;
  if (idx >= TOT) return;

  float f[8];
  __half* dst;
  if (idx < DPn) {
    int g = idx & 1; int hwi = idx >> 1; int hw = hwi & 65535; int i = hwi >> 16;
    const float* s = dp + (i * 16 + g * 8) * 65536 + hw;
#pragma unroll
    for (int k = 0; k < 8; ++k) f[k] = s[k * 65536];
    dst = ws + DPT_H + ((i * 65536 + hw) * 16 + g * 8);
  } else if (idx < DPn + APn) {
    int t = idx - DPn;
    int g = t & 3; int hwi = t >> 2; int hw = hwi & 65535; int i = hwi >> 16;
    if (g < 3) {
      const float* s = ap + (i * 24 + g * 8) * 65536 + hw;
#pragma unroll
      for (int k = 0; k < 8; ++k) f[k] = s[k * 65536];
    } else {
#pragma unroll
      for (int k = 0; k < 8; ++k) f[k] = 0.0f;
    }
    dst = ws + APT_H + ((i * 65536 + hw) * 32 + g * 8);
  } else if (idx < DPn + APn + DLn) {
    int t = idx - (DPn + APn);
    int g = t & 1; int li = t >> 1; int l = li & 255; int i = li >> 8;
    const float* s = dl + (i * 16 + g * 8) * 256 + l;
#pragma unroll
    for (int k = 0; k < 8; ++k) f[k] = s[k * 256];
    dst = ws + DLT_H + ((i * 256 + l) * 16 + g * 8);
  } else {
    int t = idx - (DPn + APn + DLn);
    int g = t & 3; int li = t >> 2; int l = li & 255; int i = li >> 8;
    if (g < 3) {
      const float* s = al + (i * 24 + g * 8) * 256 + l;
#pragma unroll
      for (int k = 0; k < 8; ++k) f[k] = s[k * 256];
    } else {
#pragma unroll
      for (int k = 0; k < 8; ++k) f[k] = 0.0f;
    }
    dst = ws + ALT_H + ((i * 256 + l) * 32 + g * 8);
  }
  uint4 v;
  v.x = pack2h(f[0], f[1]); v.y = pack2h(f[2], f[3]);
  v.z = pack2h(f[4], f[5]); v.w = pack2h(f[6], f[7]);
  *(uint4*)dst = v;
}

// ---------------------------------------------------------------------------
// density mode: lane sub owns channels sub*4..sub*4+3. 8B loads.
// ---------------------------------------------------------------------------
__device__ __forceinline__ float density_h(const __half* __restrict__ pl,
                                           const __half* __restrict__ ln,
                                           int x0, float wx, int y0, float wy,
                                           int l0, float wl, int sub) {
  const __half* p = pl + (y0 * 256 + x0) * 16 + sub * 4;
  float4 v00 = load4h(p);
  float4 v01 = load4h(p + 16);
  float4 v10 = load4h(p + 4096);
  float4 v11 = load4h(p + 4096 + 16);
  const __half* lp = ln + l0 * 16 + sub * 4;
  float4 la = load4h(lp), lb = load4h(lp + 16);
  float4 mid = lerp4(lerp4(v00, v01, wx), lerp4(v10, v11, wx), wy);
  float4 lv = lerp4(la, lb, wl);
  return dot4(mid, lv);
}

// ---------------------------------------------------------------------------
// app mode: lane sub owns channels sub*8..sub*8+7 (incl. zero pad). 16B loads.
// ---------------------------------------------------------------------------
__device__ __forceinline__ void app_h(const __half* __restrict__ pl,
                                      const __half* __restrict__ ln,
                                      const float* __restrict__ btR,
                                      const float* __restrict__ btG,
                                      const float* __restrict__ btB,
                                      int x0, float wx, int y0, float wy,
                                      int l0, float wl, int sub,
                                      float& dr, float& dg, float& db) {
  const __half* p = pl + (y0 * 256 + x0) * 32 + sub * 8;
  float4 a0, a1, b0, b1, c0, c1, d0, d1;
  load8h(p, a0, a1);
  load8h(p + 32, b0, b1);
  load8h(p + 8192, c0, c1);
  load8h(p + 8192 + 32, d0, d1);
  const __half* lp = ln + l0 * 32 + sub * 8;
  float4 la0, la1, lb0, lb1;
  load8h(lp, la0, la1);
  load8h(lp + 32, lb0, lb1);
  float4 midlo = lerp4(lerp4(a0, b0, wx), lerp4(c0, d0, wx), wy);
  float4 midhi = lerp4(lerp4(a1, b1, wx), lerp4(c1, d1, wx), wy);
  float4 lvlo = lerp4(la0, lb0, wl);
  float4 lvhi = lerp4(la1, lb1, wl);
  float4 avlo = mul4(midlo, lvlo);
  float4 avhi = mul4(midhi, lvhi);
  dr += dot4(avlo, ld4(btR)) + dot4(avhi, ld4(btR + 4));
  dg += dot4(avlo, ld4(btG)) + dot4(avhi, ld4(btG + 4));
  db += dot4(avlo, ld4(btB)) + dot4(avhi, ld4(btB + 4));
}

// ---------------------------------------------------------------------------
// Fused render: block = 1024 threads = 1 ray (256 samples x 4 lanes).
// Per-sample shade -> LDS -> wave 0 does transmittance scan -> output.
// ---------------------------------------------------------------------------
__global__ __launch_bounds__(1024, 1) void render_h_kernel(
    const float* __restrict__ rays, const float* __restrict__ basis,
    const float* __restrict__ aabb, const __half* __restrict__ ws,
    float* __restrict__ out) {
  const __half* dpt = ws + DPT_H;
  const __half* apt = ws + APT_H;
  const __half* dlt = ws + DLT_H;
  const __half* alt = ws + ALT_H;

  __shared__ __align__(16) float bt[3 * 96];   // [k][mode*32+c], pad zeroed
  __shared__ __align__(16) float4 smp[NSAMP];  // alpha, r, g, b

  int tid = threadIdx.x;
  if (tid < 216) {
    int k = tid / 72, r = tid - k * 72;
    int m = r / 24, c = r - m * 24;
    bt[k * 96 + m * 32 + c] = basis[r * 3 + k];
  } else if (tid < 288) {
    int t = tid - 216;
    int k = t / 24, p = t - k * 24;
    bt[k * 96 + (p >> 3) * 32 + 24 + (p & 7)] = 0.0f;
  }

  int ray = blockIdx.x;
  int j = tid >> 2, sub = tid & 3;

  float o0 = rays[ray * 6 + 0], o1 = rays[ray * 6 + 1], o2 = rays[ray * 6 + 2];
  float d0 = rays[ray * 6 + 3], d1 = rays[ray * 6 + 4], d2 = rays[ray * 6 + 5];
  float A0 = aabb[0], A1 = aabb[1], A2 = aabb[2];
  float B0 = aabb[3], B1 = aabb[4], B2 = aabb[5];

  float v0 = fabsf(d0) < 1e-6f ? 1e-6f : d0;
  float v1 = fabsf(d1) < 1e-6f ? 1e-6f : d1;
  float v2 = fabsf(d2) < 1e-6f ? 1e-6f : d2;
  float ra0 = (B0 - o0) / v0, rb0 = (A0 - o0) / v0;
  float ra1 = (B1 - o1) / v1, rb1 = (A1 - o1) / v1;
  float ra2 = (B2 - o2) / v2, rb2 = (A2 - o2) / v2;
  float tmin = fmaxf(fmaxf(fminf(ra0, rb0), fminf(ra1, rb1)), fminf(ra2, rb2));
  tmin = fmaxf(tmin, 0.05f);
  float tmax = fminf(fminf(fmaxf(ra0, rb0), fmaxf(ra1, rb1)), fmaxf(ra2, rb2));
  tmax = fmaxf(tmax, tmin + 0.001f);
  float dt = (tmax - tmin) * (1.0f / 255.0f);

  float s0 = 2.0f / (B0 - A0), s1 = 2.0f / (B1 - A1), s2 = 2.0f / (B2 - A2);
  float sfrac = (float)j * (1.0f / 255.0f);
  float z = tmin * (1.0f - sfrac) + tmax * sfrac;
  float c0 = (o0 + d0 * z - A0) * s0 - 1.0f;
  float c1 = (o1 + d1 * z - A1) * s1 - 1.0f;
  float c2 = (o2 + d2 * z - A2) * s2 - 1.0f;
  bool inside = (fabsf(c0) <= 1.0f) && (fabsf(c1) <= 1.0f) && (fabsf(c2) <= 1.0f);

  __syncthreads();  // basis table ready

  float sig = 0.f, dr = 0.f, dg = 0.f, db = 0.f;
  if (inside) {
    int i0, i1, i2; float w0, w1, w2;
    grid_uv(c0, i0, w0);
    grid_uv(c1, i1, w1);
    grid_uv(c2, i2, w2);
    // MAT_MODE = [(0,1),(0,2),(1,2)], VEC_MODE = [2,1,0]
    sig += density_h(dpt + 0 * 1048576, dlt + 0 * 4096, i0, w0, i1, w1, i2, w2, sub);
    sig += density_h(dpt + 1 * 1048576, dlt + 1 * 4096, i0, w0, i2, w2, i1, w1, sub);
    sig += density_h(dpt + 2 * 1048576, dlt + 2 * 4096, i1, w1, i2, w2, i0, w0, sub);
    int bo = sub * 8;
    app_h(apt + 0 * 2097152, alt + 0 * 8192,
          &bt[0 * 96 + 0 * 32 + bo], &bt[1 * 96 + 0 * 32 + bo], &bt[2 * 96 + 0 * 32 + bo],
          i0, w0, i1, w1, i2, w2, sub, dr, dg, db);
    app_h(apt + 1 * 2097152, alt + 1 * 8192,
          &bt[0 * 96 + 1 * 32 + bo], &bt[1 * 96 + 1 * 32 + bo], &bt[2 * 96 + 1 * 32 + bo],
          i0, w0, i2, w2, i1, w1, sub, dr, dg, db);
    app_h(apt + 2 * 2097152, alt + 2 * 8192,
          &bt[0 * 96 + 2 * 32 + bo], &bt[1 * 96 + 2 * 32 + bo], &bt[2 * 96 + 2 * 32 + bo],
          i1, w1, i2, w2, i0, w0, sub, dr, dg, db);
  }
  // reduce over the 4-lane group
  sig += __shfl_xor(sig, 1, 64); sig += __shfl_xor(sig, 2, 64);
  dr  += __shfl_xor(dr, 1, 64);  dr  += __shfl_xor(dr, 2, 64);
  dg  += __shfl_xor(dg, 1, 64);  dg  += __shfl_xor(dg, 2, 64);
  db  += __shfl_xor(db, 1, 64);  db  += __shfl_xor(db, 2, 64);

  if (sub == 0) {
    float sp = fmaxf(sig, 0.f) + log1pf(expf(-fabsf(sig)));  // softplus
    float4 outv;
    outv.x = inside ? (1.0f - expf(-sp * dt)) : 0.0f;
    outv.y = 1.0f / (1.0f + expf(-dr));
    outv.z = 1.0f / (1.0f + expf(-dg));
    outv.w = 1.0f / (1.0f + expf(-db));
    smp[j] = outv;
  }
  __syncthreads();

  // wave 0: transmittance scan + composite over the 256 samples
  if (tid < 64) {
    int lane = tid;
    float C = 1.0f;
    float racc = 0.f, gacc = 0.f, bacc = 0.f, wsum = 0.f, dsum = 0.f;
    for (int q = 0; q < 4; ++q) {
      int jj = q * 64 + lane;
      float4 sv = smp[jj];
      float alpha = sv.x;
      float sf = (float)jj * (1.0f / 255.0f);
      float zz = tmin * (1.0f - sf) + tmax * sf;
      float p = 1.0f - alpha + 1e-10f;
#pragma unroll
      for (int off = 1; off < 64; off <<= 1) {
        float t = __shfl_up(p, off, 64);
        if (lane >= off) p *= t;
      }
      float tot = __shfl(p, 63, 64);
      float e = __shfl_up(p, 1, 64);
      if (lane == 0) e = 1.0f;
      float Tj = C * e;
      float w = alpha * Tj;
      racc += w * sv.y; gacc += w * sv.z; bacc += w * sv.w;
      wsum += w; dsum += w * zz;
      C *= tot;
    }
#pragma unroll
    for (int off = 32; off > 0; off >>= 1) {
      racc += __shfl_down(racc, off, 64);
      gacc += __shfl_down(gacc, off, 64);
      bacc += __shfl_down(bacc, off, 64);
      wsum += __shfl_down(wsum, off, 64);
      dsum += __shfl_down(dsum, off, 64);
    }
    if (lane == 0) {
      float bgw = 1.0f - wsum;  // WHITE_BG
      out[ray * 3 + 0] = fminf(fmaxf(racc + bgw, 0.f), 1.f);
      out[ray * 3 + 1] = fminf(fmaxf(gacc + bgw, 0.f), 1.f);
      out[ray * 3 + 2] = fminf(fmaxf(bacc + bgw, 0.f), 1.f);
      out[NRAYS * 3 + ray] = dsum;
    }
  }
}

// ---------------------------------------------------------------------------
// Fallback (ws too small): single-kernel fp32 render on original layout.
// ---------------------------------------------------------------------------
__device__ __forceinline__ float density_orig(const float* __restrict__ plane,
                                              const float* __restrict__ line,
                                              float cx, float cy, float cw) {
  int x0, y0, l0; float wx, wy, wl;
  grid_uv(cx, x0, wx); grid_uv(cy, y0, wy); grid_uv(cw, l0, wl);
  int base = y0 * 256 + x0;
  float s = 0.0f;
#pragma unroll 4
  for (int c = 0; c < 16; ++c) {
    const float* pc = plane + c * 65536;
    float v00 = pc[base], v01 = pc[base + 1];
    float v10 = pc[base + 256], v11 = pc[base + 257];
    float top = fmaf(wx, v01 - v00, v00);
    float bot = fmaf(wx, v11 - v10, v10);
    float mid = fmaf(wy, bot - top, top);
    float la = line[c * 256 + l0], lb = line[c * 256 + l0 + 1];
    float lv = fmaf(wl, lb - la, la);
    s += mid * lv;
  }
  return s;
}

__device__ __forceinline__ void app_orig(const float* __restrict__ plane,
                                         const float* __restrict__ line,
                                         const float* __restrict__ btR,
                                         const float* __restrict__ btG,
                                         const float* __restrict__ btB,
                                         float cx, float cy, float cw,
                                         float& dr, float& dg, float& db) {
  int x0, y0, l0; float wx, wy, wl;
  grid_uv(cx, x0, wx); grid_uv(cy, y0, wy); grid_uv(cw, l0, wl);
  int base = y0 * 256 + x0;
#pragma unroll 4
  for (int c = 0; c < 24; ++c) {
    const float* pc = plane + c * 65536;
    float v00 = pc[base], v01 = pc[base + 1];
    float v10 = pc[base + 256], v11 = pc[base + 257];
    float top = fmaf(wx, v01 - v00, v00);
    float bot = fmaf(wx, v11 - v10, v10);
    float mid = fmaf(wy, bot - top, top);
    float la = line[c * 256 + l0], lb = line[c * 256 + l0 + 1];
    float lv = fmaf(wl, lb - la, la);
    float av = mid * lv;
    dr += av * btR[c]; dg += av * btG[c]; db += av * btB[c];
  }
}

__global__ __launch_bounds__(256) void render_fallback(
    const float* __restrict__ rays, const float* __restrict__ basis,
    const float* __restrict__ aabb, const float* __restrict__ dplane,
    const float* __restrict__ dline, const float* __restrict__ aplane,
    const float* __restrict__ aline, float* __restrict__ out) {
  __shared__ float bt[3 * 72];
  int tid = threadIdx.x;
  if (tid < 216) {
    int k = tid / 72, r = tid - k * 72;
    bt[tid] = basis[r * 3 + k];
  }
  __syncthreads();
  int lane = tid & 63;
  int ray = blockIdx.x * 4 + (tid >> 6);

  float o0 = rays[ray * 6 + 0], o1 = rays[ray * 6 + 1], o2 = rays[ray * 6 + 2];
  float d0 = rays[ray * 6 + 3], d1 = rays[ray * 6 + 4], d2 = rays[ray * 6 + 5];
  float A0 = aabb[0], A1 = aabb[1], A2 = aabb[2];
  float B0 = aabb[3], B1 = aabb[4], B2 = aabb[5];
  float v0 = fabsf(d0) < 1e-6f ? 1e-6f : d0;
  float v1 = fabsf(d1) < 1e-6f ? 1e-6f : d1;
  float v2 = fabsf(d2) < 1e-6f ? 1e-6f : d2;
  float ra0 = (B0 - o0) / v0, rb0 = (A0 - o0) / v0;
  float ra1 = (B1 - o1) / v1, rb1 = (A1 - o1) / v1;
  float ra2 = (B2 - o2) / v2, rb2 = (A2 - o2) / v2;
  float tmin = fmaxf(fmaxf(fminf(ra0, rb0), fminf(ra1, rb1)), fminf(ra2, rb2));
  tmin = fmaxf(tmin, 0.05f);
  float tmax = fminf(fminf(fmaxf(ra0, rb0), fmaxf(ra1, rb1)), fmaxf(ra2, rb2));
  tmax = fmaxf(tmax, tmin + 0.001f);
  float dt = (tmax - tmin) * (1.0f / 255.0f);
  float s0 = 2.0f / (B0 - A0), s1 = 2.0f / (B1 - A1), s2 = 2.0f / (B2 - A2);

  float C = 1.0f;
  float racc = 0.f, gacc = 0.f, bacc = 0.f, wsum = 0.f, dsum = 0.f;
  for (int q = 0; q < 4; ++q) {
    int j = q * 64 + lane;
    float sfrac = (float)j * (1.0f / 255.0f);
    float z = tmin * (1.0f - sfrac) + tmax * sfrac;
    float c0 = (o0 + d0 * z - A0) * s0 - 1.0f;
    float c1 = (o1 + d1 * z - A1) * s1 - 1.0f;
    float c2 = (o2 + d2 * z - A2) * s2 - 1.0f;
    bool inside = (fabsf(c0) <= 1.0f) && (fabsf(c1) <= 1.0f) && (fabsf(c2) <= 1.0f);
    float alpha = 0.f, cr = 0.f, cg = 0.f, cb = 0.f;
    if (inside) {
      float sig = 0.f, dr = 0.f, dg = 0.f, db = 0.f;
      sig += density_orig(dplane + 0 * 1048576, dline + 0 * 4096, c0, c1, c2);
      sig += density_orig(dplane + 1 * 1048576, dline + 1 * 4096, c0, c2, c1);
      sig += density_orig(dplane + 2 * 1048576, dline + 2 * 4096, c1, c2, c0);
      app_orig(aplane + 0 * 1572864, aline + 0 * 6144,
               &bt[0 * 72 + 0], &bt[1 * 72 + 0], &bt[2 * 72 + 0],
               c0, c1, c2, dr, dg, db);
      app_orig(aplane + 1 * 1572864, aline + 1 * 6144,
               &bt[0 * 72 + 24], &bt[1 * 72 + 24], &bt[2 * 72 + 24],
               c0, c2, c1, dr, dg, db);
      app_orig(aplane + 2 * 1572864, aline + 2 * 6144,
               &bt[0 * 72 + 48], &bt[1 * 72 + 48], &bt[2 * 72 + 48],
               c1, c2, c0, dr, dg, db);
      float sp = fmaxf(sig, 0.f) + log1pf(expf(-fabsf(sig)));
      alpha = 1.0f - expf(-sp * dt);
      cr = 1.0f / (1.0f + expf(-dr));
      cg = 1.0f / (1.0f + expf(-dg));
      cb = 1.0f / (1.0f + expf(-db));
    }
    float p = 1.0f - alpha + 1e-10f;
#pragma unroll
    for (int off = 1; off < 64; off <<= 1) {
      float t = __shfl_up(p, off, 64);
      if (lane >= off) p *= t;
    }
    float tot = __shfl(p, 63, 64);
    float e = __shfl_up(p, 1, 64);
    if (lane == 0) e = 1.0f;
    float Tj = C * e;
    float w = alpha * Tj;
    racc += w * cr; gacc += w * cg; bacc += w * cb;
    wsum += w; dsum += w * z;
    C *= tot;
  }
#pragma unroll
  for (int off = 32; off > 0; off >>= 1) {
    racc += __shfl_down(racc, off, 64);
    gacc += __shfl_down(gacc, off, 64);
    bacc += __shfl_down(bacc, off, 64);
    wsum += __shfl_down(wsum, off, 64);
    dsum += __shfl_down(dsum, off, 64);
  }
  if (lane == 0) {
    float bgw = 1.0f - wsum;
    out[ray * 3 + 0] = fminf(fmaxf(racc + bgw, 0.f), 1.f);
    out[ray * 3 + 1] = fminf(fmaxf(gacc + bgw, 0.f), 1.f);
    out[ray * 3 + 2] = fminf(fmaxf(bacc + bgw, 0.f), 1.f);
    out[NRAYS * 3 + ray] = dsum;
  }
}

extern "C" void kernel_launch(void* const* d_in, const int* in_sizes, int n_in,
                              void* d_out, int out_size, void* d_ws, size_t ws_size,
                              hipStream_t stream) {
  const float* rays  = (const float*)d_in[0];
  const float* dp    = (const float*)d_in[1];
  const float* dl    = (const float*)d_in[2];
  const float* ap    = (const float*)d_in[3];
  const float* al    = (const float*)d_in[4];
  const float* basis = (const float*)d_in[5];
  const float* aabb  = (const float*)d_in[6];
  float* out = (float*)d_out;

  if (ws_size >= WS_NEED) {
    __half* ws = (__half*)d_ws;
    transpose_h_kernel<<<4626, 256, 0, stream>>>(dp, dl, ap, al, ws);
    render_h_kernel<<<NRAYS, 1024, 0, stream>>>(rays, basis, aabb, ws, out);
  } else {
    render_fallback<<<NRAYS / 4, 256, 0, stream>>>(
        rays, basis, aabb, dp, dl, ap, al, out);
  }
}

// Round 4
// 217.645 us; speedup vs baseline: 1.2979x; 1.2979x over previous
//
#include <hip/hip_runtime.h>
#include <hip/hip_fp16.h>
#include <cmath>

#define NRAYS 4096
#define NSAMP 256
#define NSAMPLES_TOT (NRAYS * NSAMP)

// Workspace layout (byte offsets):
//   dpt fp16 [i][y][x][16]   3*65536*16*2 = 6291456
//   dlt fp16 [i][l][16]      3*256*16*2   = 24576
//   apt fp8  [i][y][x][32]   3*65536*32   = 6291456   (ch24..31 zero pad)
//   alt fp8  [i][l][32]      3*256*32     = 24576
//   smp float4 [ray][samp]   1048576*16   = 16777216
static constexpr size_t DPT_B = 0;
static constexpr size_t DLT_B = 6291456;
static constexpr size_t APT_B = DLT_B + 24576;      // 6316032
static constexpr size_t ALT_B = APT_B + 6291456;    // 12607488
static constexpr size_t SMP_B = ALT_B + 24576;      // 12632064 (16B aligned)
static constexpr size_t WS_NEED = SMP_B + 16777216; // ~29.4 MB

typedef __attribute__((ext_vector_type(2))) float f32x2;

__device__ __forceinline__ float4 ld4(const float* p) { return *(const float4*)p; }

__device__ __forceinline__ float4 lerp4(float4 a, float4 b, float w) {
  float4 o;
  o.x = fmaf(w, b.x - a.x, a.x);
  o.y = fmaf(w, b.y - a.y, a.y);
  o.z = fmaf(w, b.z - a.z, a.z);
  o.w = fmaf(w, b.w - a.w, a.w);
  return o;
}

__device__ __forceinline__ float4 mul4(float4 a, float4 b) {
  float4 o; o.x = a.x*b.x; o.y = a.y*b.y; o.z = a.z*b.z; o.w = a.w*b.w; return o;
}

__device__ __forceinline__ float dot4(float4 a, float4 b) {
  return a.x * b.x + a.y * b.y + a.z * b.z + a.w * b.w;
}

// align_corners=True grid coord -> (i0, frac). N=256 fixed.
__device__ __forceinline__ void grid_uv(float c, int& i0, float& w) {
  float f = (c + 1.0f) * 127.5f;
  float fl = floorf(f);
  fl = fminf(fmaxf(fl, 0.0f), 254.0f);
  i0 = (int)fl;
  w = f - fl;
}

// 8B load of 4 halves -> float4
__device__ __forceinline__ float4 load4h(const __half* p) {
  uint2 raw = *(const uint2*)p;
  float2 f0 = __half22float2(__builtin_bit_cast(__half2, raw.x));
  float2 f1 = __half22float2(__builtin_bit_cast(__half2, raw.y));
  return make_float4(f0.x, f0.y, f1.x, f1.y);
}

__device__ __forceinline__ unsigned pack2h(float a, float b) {
  return __builtin_bit_cast(unsigned, __floats2half2_rn(a, b));
}

// 4 fp8(e4m3) bytes in dword -> float4 (HW cvt)
__device__ __forceinline__ float4 dec4f8(unsigned w) {
  f32x2 a = __builtin_amdgcn_cvt_pk_f32_fp8((int)w, false);
  f32x2 b = __builtin_amdgcn_cvt_pk_f32_fp8((int)w, true);
  return make_float4(a.x, a.y, b.x, b.y);
}

// 4 floats -> dword of 4 fp8(e4m3) bytes
__device__ __forceinline__ unsigned pk4f8(float a, float b, float c, float d) {
  int w = __builtin_amdgcn_cvt_pk_fp8_f32(a, b, 0, false);
  w = __builtin_amdgcn_cvt_pk_fp8_f32(c, d, w, true);
  return (unsigned)w;
}

// ---------------------------------------------------------------------------
// Plane transpose: one block per (plane, y) row. Coalesced reads (rows of
// 256 floats), LDS transpose, coalesced 32B/thread stores.
// blocks [0,768): density fp16; [768,1536): app fp8.
// ---------------------------------------------------------------------------
__global__ __launch_bounds__(256) void transpose_planes(
    const float* __restrict__ dp, const float* __restrict__ ap,
    __half* __restrict__ dpt, unsigned char* __restrict__ apt) {
  __shared__ float tile[24][257];
  int b = blockIdx.x, x = threadIdx.x;
  if (b < 768) {
    int i = b >> 8, y = b & 255;
    const float* src = dp + (size_t)(i * 16) * 65536 + y * 256;
#pragma unroll
    for (int c = 0; c < 16; ++c) tile[c][x] = src[c * 65536 + x];
    __syncthreads();
    float f[16];
#pragma unroll
    for (int c = 0; c < 16; ++c) f[c] = tile[c][x];
    uint4 v0, v1;
    v0.x = pack2h(f[0], f[1]);   v0.y = pack2h(f[2], f[3]);
    v0.z = pack2h(f[4], f[5]);   v0.w = pack2h(f[6], f[7]);
    v1.x = pack2h(f[8], f[9]);   v1.y = pack2h(f[10], f[11]);
    v1.z = pack2h(f[12], f[13]); v1.w = pack2h(f[14], f[15]);
    uint4* dst = (uint4*)(dpt + ((size_t)(i << 16) + (y << 8) + x) * 16);
    dst[0] = v0; dst[1] = v1;
  } else {
    int t = b - 768;
    int i = t >> 8, y = t & 255;
    const float* src = ap + (size_t)(i * 24) * 65536 + y * 256;
#pragma unroll
    for (int c = 0; c < 24; ++c) tile[c][x] = src[c * 65536 + x];
    __syncthreads();
    float f[24];
#pragma unroll
    for (int c = 0; c < 24; ++c) f[c] = tile[c][x];
    uint4 v0, v1;
    v0.x = pk4f8(f[0], f[1], f[2], f[3]);
    v0.y = pk4f8(f[4], f[5], f[6], f[7]);
    v0.z = pk4f8(f[8], f[9], f[10], f[11]);
    v0.w = pk4f8(f[12], f[13], f[14], f[15]);
    v1.x = pk4f8(f[16], f[17], f[18], f[19]);
    v1.y = pk4f8(f[20], f[21], f[22], f[23]);
    v1.z = 0u; v1.w = 0u;
    uint4* dst = (uint4*)(apt + ((size_t)(i << 16) + (y << 8) + x) * 32);
    dst[0] = v0; dst[1] = v1;
  }
}

// ---------------------------------------------------------------------------
// Line transpose (tiny): blocks 0-2 density fp16, 3-5 app fp8. thread = l.
// ---------------------------------------------------------------------------
__global__ __launch_bounds__(256) void transpose_lines(
    const float* __restrict__ dl, const float* __restrict__ al,
    __half* __restrict__ dlt, unsigned char* __restrict__ alt) {
  int b = blockIdx.x, l = threadIdx.x;
  if (b < 3) {
    int i = b;
    float f[16];
#pragma unroll
    for (int c = 0; c < 16; ++c) f[c] = dl[(i * 16 + c) * 256 + l];
    uint4 v0, v1;
    v0.x = pack2h(f[0], f[1]);   v0.y = pack2h(f[2], f[3]);
    v0.z = pack2h(f[4], f[5]);   v0.w = pack2h(f[6], f[7]);
    v1.x = pack2h(f[8], f[9]);   v1.y = pack2h(f[10], f[11]);
    v1.z = pack2h(f[12], f[13]); v1.w = pack2h(f[14], f[15]);
    uint4* dst = (uint4*)(dlt + (i * 256 + l) * 16);
    dst[0] = v0; dst[1] = v1;
  } else {
    int i = b - 3;
    float f[24];
#pragma unroll
    for (int c = 0; c < 24; ++c) f[c] = al[(i * 24 + c) * 256 + l];
    uint4 v0, v1;
    v0.x = pk4f8(f[0], f[1], f[2], f[3]);
    v0.y = pk4f8(f[4], f[5], f[6], f[7]);
    v0.z = pk4f8(f[8], f[9], f[10], f[11]);
    v0.w = pk4f8(f[12], f[13], f[14], f[15]);
    v1.x = pk4f8(f[16], f[17], f[18], f[19]);
    v1.y = pk4f8(f[20], f[21], f[22], f[23]);
    v1.z = 0u; v1.w = 0u;
    uint4* dst = (uint4*)(alt + (i * 256 + l) * 32);
    dst[0] = v0; dst[1] = v1;
  }
}

// ---------------------------------------------------------------------------
// density mode (fp16): lane sub owns channels sub*4..sub*4+3. 8B loads.
// ---------------------------------------------------------------------------
__device__ __forceinline__ float density_h(const __half* __restrict__ pl,
                                           const __half* __restrict__ ln,
                                           int x0, float wx, int y0, float wy,
                                           int l0, float wl, int sub) {
  const __half* p = pl + (y0 * 256 + x0) * 16 + sub * 4;
  float4 v00 = load4h(p);
  float4 v01 = load4h(p + 16);
  float4 v10 = load4h(p + 4096);
  float4 v11 = load4h(p + 4096 + 16);
  const __half* lp = ln + l0 * 16 + sub * 4;
  float4 la = load4h(lp), lb = load4h(lp + 16);
  float4 mid = lerp4(lerp4(v00, v01, wx), lerp4(v10, v11, wx), wy);
  float4 lv = lerp4(la, lb, wl);
  return dot4(mid, lv);
}

// ---------------------------------------------------------------------------
// app mode (fp8): lane sub owns channels sub*8..sub*8+7 (incl pad). 8B loads.
// ---------------------------------------------------------------------------
__device__ __forceinline__ void app8(const unsigned char* __restrict__ pl,
                                     const unsigned char* __restrict__ ln,
                                     const float* __restrict__ btR,
                                     const float* __restrict__ btG,
                                     const float* __restrict__ btB,
                                     int x0, float wx, int y0, float wy,
                                     int l0, float wl, int sub,
                                     float& dr, float& dg, float& db) {
  const unsigned char* p = pl + (size_t)(y0 * 256 + x0) * 32 + sub * 8;
  uint2 q00 = *(const uint2*)p;
  uint2 q01 = *(const uint2*)(p + 32);
  uint2 q10 = *(const uint2*)(p + 8192);
  uint2 q11 = *(const uint2*)(p + 8192 + 32);
  const unsigned char* lp = ln + l0 * 32 + sub * 8;
  uint2 qa = *(const uint2*)lp;
  uint2 qb = *(const uint2*)(lp + 32);

  float4 a0 = dec4f8(q00.x), a1 = dec4f8(q00.y);
  float4 b0 = dec4f8(q01.x), b1 = dec4f8(q01.y);
  float4 c0 = dec4f8(q10.x), c1 = dec4f8(q10.y);
  float4 d0 = dec4f8(q11.x), d1 = dec4f8(q11.y);
  float4 la0 = dec4f8(qa.x), la1 = dec4f8(qa.y);
  float4 lb0 = dec4f8(qb.x), lb1 = dec4f8(qb.y);

  float4 midlo = lerp4(lerp4(a0, b0, wx), lerp4(c0, d0, wx), wy);
  float4 midhi = lerp4(lerp4(a1, b1, wx), lerp4(c1, d1, wx), wy);
  float4 lvlo = lerp4(la0, lb0, wl);
  float4 lvhi = lerp4(la1, lb1, wl);
  float4 avlo = mul4(midlo, lvlo);
  float4 avhi = mul4(midhi, lvhi);
  dr += dot4(avlo, ld4(btR)) + dot4(avhi, ld4(btR + 4));
  dg += dot4(avlo, ld4(btG)) + dot4(avhi, ld4(btG + 4));
  db += dot4(avlo, ld4(btB)) + dot4(avhi, ld4(btB + 4));
}

// ---------------------------------------------------------------------------
// Sample kernel: 4 lanes per sample, 256-thread blocks, 16384 blocks.
// Each wave = 16 consecutive samples of one ray.
// ---------------------------------------------------------------------------
__global__ __launch_bounds__(256) void sample_kernel(
    const float* __restrict__ rays, const float* __restrict__ basis,
    const float* __restrict__ aabb, const __half* __restrict__ dpt,
    const __half* __restrict__ dlt, const unsigned char* __restrict__ apt,
    const unsigned char* __restrict__ alt, float4* __restrict__ smp) {
  __shared__ __align__(16) float bt[3 * 96];  // [k][mode*32+c], pad zeroed
  int tid = threadIdx.x;
  if (tid < 216) {
    int k = tid / 72, r = tid - k * 72;
    int m = r / 24, c = r - m * 24;
    bt[k * 96 + m * 32 + c] = basis[r * 3 + k];
  }
  if (tid < 72) {
    int k = tid / 24, t = tid - k * 24;
    bt[k * 96 + (t >> 3) * 32 + 24 + (t & 7)] = 0.0f;
  }
  __syncthreads();

  int g = (blockIdx.x * 256 + tid) >> 2;  // sample index
  int sub = tid & 3;
  int ray = g >> 8, j = g & 255;

  float o0 = rays[ray * 6 + 0], o1 = rays[ray * 6 + 1], o2 = rays[ray * 6 + 2];
  float d0 = rays[ray * 6 + 3], d1 = rays[ray * 6 + 4], d2 = rays[ray * 6 + 5];
  float A0 = aabb[0], A1 = aabb[1], A2 = aabb[2];
  float B0 = aabb[3], B1 = aabb[4], B2 = aabb[5];

  float v0 = fabsf(d0) < 1e-6f ? 1e-6f : d0;
  float v1 = fabsf(d1) < 1e-6f ? 1e-6f : d1;
  float v2 = fabsf(d2) < 1e-6f ? 1e-6f : d2;
  float ra0 = (B0 - o0) / v0, rb0 = (A0 - o0) / v0;
  float ra1 = (B1 - o1) / v1, rb1 = (A1 - o1) / v1;
  float ra2 = (B2 - o2) / v2, rb2 = (A2 - o2) / v2;
  float tmin = fmaxf(fmaxf(fminf(ra0, rb0), fminf(ra1, rb1)), fminf(ra2, rb2));
  tmin = fmaxf(tmin, 0.05f);
  float tmax = fminf(fminf(fmaxf(ra0, rb0), fmaxf(ra1, rb1)), fmaxf(ra2, rb2));
  tmax = fmaxf(tmax, tmin + 0.001f);
  float dt = (tmax - tmin) * (1.0f / 255.0f);

  float s0 = 2.0f / (B0 - A0), s1 = 2.0f / (B1 - A1), s2 = 2.0f / (B2 - A2);
  float sfrac = (float)j * (1.0f / 255.0f);
  float z = tmin * (1.0f - sfrac) + tmax * sfrac;
  float c0 = (o0 + d0 * z - A0) * s0 - 1.0f;
  float c1 = (o1 + d1 * z - A1) * s1 - 1.0f;
  float c2 = (o2 + d2 * z - A2) * s2 - 1.0f;
  bool inside = (fabsf(c0) <= 1.0f) && (fabsf(c1) <= 1.0f) && (fabsf(c2) <= 1.0f);

  float sig = 0.f, dr = 0.f, dg = 0.f, db = 0.f;
  if (inside) {
    int i0, i1, i2; float w0, w1, w2;
    grid_uv(c0, i0, w0);
    grid_uv(c1, i1, w1);
    grid_uv(c2, i2, w2);
    // MAT_MODE = [(0,1),(0,2),(1,2)], VEC_MODE = [2,1,0]
    sig += density_h(dpt + 0 * 1048576, dlt + 0 * 4096, i0, w0, i1, w1, i2, w2, sub);
    sig += density_h(dpt + 1 * 1048576, dlt + 1 * 4096, i0, w0, i2, w2, i1, w1, sub);
    sig += density_h(dpt + 2 * 1048576, dlt + 2 * 4096, i1, w1, i2, w2, i0, w0, sub);
    int bo = sub * 8;
    app8(apt + 0 * 2097152, alt + 0 * 8192,
         &bt[0 * 96 + 0 * 32 + bo], &bt[1 * 96 + 0 * 32 + bo], &bt[2 * 96 + 0 * 32 + bo],
         i0, w0, i1, w1, i2, w2, sub, dr, dg, db);
    app8(apt + 1 * 2097152, alt + 1 * 8192,
         &bt[0 * 96 + 1 * 32 + bo], &bt[1 * 96 + 1 * 32 + bo], &bt[2 * 96 + 1 * 32 + bo],
         i0, w0, i2, w2, i1, w1, sub, dr, dg, db);
    app8(apt + 2 * 2097152, alt + 2 * 8192,
         &bt[0 * 96 + 2 * 32 + bo], &bt[1 * 96 + 2 * 32 + bo], &bt[2 * 96 + 2 * 32 + bo],
         i1, w1, i2, w2, i0, w0, sub, dr, dg, db);
  }
  // reduce over the 4-lane group
  sig += __shfl_xor(sig, 1, 64); sig += __shfl_xor(sig, 2, 64);
  dr  += __shfl_xor(dr, 1, 64);  dr  += __shfl_xor(dr, 2, 64);
  dg  += __shfl_xor(dg, 1, 64);  dg  += __shfl_xor(dg, 2, 64);
  db  += __shfl_xor(db, 1, 64);  db  += __shfl_xor(db, 2, 64);

  if (sub == 0) {
    float sp = fmaxf(sig, 0.f) + log1pf(expf(-fabsf(sig)));  // softplus
    float4 outv;
    outv.x = inside ? (1.0f - expf(-sp * dt)) : 0.0f;
    outv.y = 1.0f / (1.0f + expf(-dr));
    outv.z = 1.0f / (1.0f + expf(-dg));
    outv.w = 1.0f / (1.0f + expf(-db));
    smp[g] = outv;
  }
}

// ---------------------------------------------------------------------------
// Scan kernel: per-ray transmittance scan + composite. One wave per ray.
// ---------------------------------------------------------------------------
__global__ __launch_bounds__(256) void scan_kernel(
    const float* __restrict__ rays, const float* __restrict__ aabb,
    const float4* __restrict__ smp, float* __restrict__ out) {
  int tid = threadIdx.x;
  int lane = tid & 63;
  int ray = blockIdx.x * 4 + (tid >> 6);

  float o0 = rays[ray * 6 + 0], o1 = rays[ray * 6 + 1], o2 = rays[ray * 6 + 2];
  float d0 = rays[ray * 6 + 3], d1 = rays[ray * 6 + 4], d2 = rays[ray * 6 + 5];
  float A0 = aabb[0], A1 = aabb[1], A2 = aabb[2];
  float B0 = aabb[3], B1 = aabb[4], B2 = aabb[5];
  float v0 = fabsf(d0) < 1e-6f ? 1e-6f : d0;
  float v1 = fabsf(d1) < 1e-6f ? 1e-6f : d1;
  float v2 = fabsf(d2) < 1e-6f ? 1e-6f : d2;
  float ra0 = (B0 - o0) / v0, rb0 = (A0 - o0) / v0;
  float ra1 = (B1 - o1) / v1, rb1 = (A1 - o1) / v1;
  float ra2 = (B2 - o2) / v2, rb2 = (A2 - o2) / v2;
  float tmin = fmaxf(fmaxf(fminf(ra0, rb0), fminf(ra1, rb1)), fminf(ra2, rb2));
  tmin = fmaxf(tmin, 0.05f);
  float tmax = fminf(fminf(fmaxf(ra0, rb0), fmaxf(ra1, rb1)), fmaxf(ra2, rb2));
  tmax = fmaxf(tmax, tmin + 0.001f);

  float C = 1.0f;
  float racc = 0.f, gacc = 0.f, bacc = 0.f, wsum = 0.f, dsum = 0.f;

  for (int q = 0; q < 4; ++q) {
    int j = q * 64 + lane;
    float4 sv = smp[ray * 256 + j];
    float alpha = sv.x;
    float sfrac = (float)j * (1.0f / 255.0f);
    float z = tmin * (1.0f - sfrac) + tmax * sfrac;

    float p = 1.0f - alpha + 1e-10f;
#pragma unroll
    for (int off = 1; off < 64; off <<= 1) {
      float t = __shfl_up(p, off, 64);
      if (lane >= off) p *= t;
    }
    float tot = __shfl(p, 63, 64);
    float e = __shfl_up(p, 1, 64);
    if (lane == 0) e = 1.0f;
    float Tj = C * e;
    float w = alpha * Tj;
    racc += w * sv.y; gacc += w * sv.z; bacc += w * sv.w;
    wsum += w; dsum += w * z;
    C *= tot;
  }

#pragma unroll
  for (int off = 32; off > 0; off >>= 1) {
    racc += __shfl_down(racc, off, 64);
    gacc += __shfl_down(gacc, off, 64);
    bacc += __shfl_down(bacc, off, 64);
    wsum += __shfl_down(wsum, off, 64);
    dsum += __shfl_down(dsum, off, 64);
  }
  if (lane == 0) {
    float bgw = 1.0f - wsum;  // WHITE_BG
    out[ray * 3 + 0] = fminf(fmaxf(racc + bgw, 0.f), 1.f);
    out[ray * 3 + 1] = fminf(fmaxf(gacc + bgw, 0.f), 1.f);
    out[ray * 3 + 2] = fminf(fmaxf(bacc + bgw, 0.f), 1.f);
    out[NRAYS * 3 + ray] = dsum;
  }
}

// ---------------------------------------------------------------------------
// Fallback (ws too small): single-kernel fp32 render on original layout.
// ---------------------------------------------------------------------------
__device__ __forceinline__ float density_orig(const float* __restrict__ plane,
                                              const float* __restrict__ line,
                                              float cx, float cy, float cw) {
  int x0, y0, l0; float wx, wy, wl;
  grid_uv(cx, x0, wx); grid_uv(cy, y0, wy); grid_uv(cw, l0, wl);
  int base = y0 * 256 + x0;
  float s = 0.0f;
#pragma unroll 4
  for (int c = 0; c < 16; ++c) {
    const float* pc = plane + c * 65536;
    float v00 = pc[base], v01 = pc[base + 1];
    float v10 = pc[base + 256], v11 = pc[base + 257];
    float top = fmaf(wx, v01 - v00, v00);
    float bot = fmaf(wx, v11 - v10, v10);
    float mid = fmaf(wy, bot - top, top);
    float la = line[c * 256 + l0], lb = line[c * 256 + l0 + 1];
    float lv = fmaf(wl, lb - la, la);
    s += mid * lv;
  }
  return s;
}

__device__ __forceinline__ void app_orig(const float* __restrict__ plane,
                                         const float* __restrict__ line,
                                         const float* __restrict__ btR,
                                         const float* __restrict__ btG,
                                         const float* __restrict__ btB,
                                         float cx, float cy, float cw,
                                         float& dr, float& dg, float& db) {
  int x0, y0, l0; float wx, wy, wl;
  grid_uv(cx, x0, wx); grid_uv(cy, y0, wy); grid_uv(cw, l0, wl);
  int base = y0 * 256 + x0;
#pragma unroll 4
  for (int c = 0; c < 24; ++c) {
    const float* pc = plane + c * 65536;
    float v00 = pc[base], v01 = pc[base + 1];
    float v10 = pc[base + 256], v11 = pc[base + 257];
    float top = fmaf(wx, v01 - v00, v00);
    float bot = fmaf(wx, v11 - v10, v10);
    float mid = fmaf(wy, bot - top, top);
    float la = line[c * 256 + l0], lb = line[c * 256 + l0 + 1];
    float lv = fmaf(wl, lb - la, la);
    float av = mid * lv;
    dr += av * btR[c]; dg += av * btG[c]; db += av * btB[c];
  }
}

__global__ __launch_bounds__(256) void render_fallback(
    const float* __restrict__ rays, const float* __restrict__ basis,
    const float* __restrict__ aabb, const float* __restrict__ dplane,
    const float* __restrict__ dline, const float* __restrict__ aplane,
    const float* __restrict__ aline, float* __restrict__ out) {
  __shared__ float bt[3 * 72];
  int tid = threadIdx.x;
  if (tid < 216) {
    int k = tid / 72, r = tid - k * 72;
    bt[tid] = basis[r * 3 + k];
  }
  __syncthreads();
  int lane = tid & 63;
  int ray = blockIdx.x * 4 + (tid >> 6);

  float o0 = rays[ray * 6 + 0], o1 = rays[ray * 6 + 1], o2 = rays[ray * 6 + 2];
  float d0 = rays[ray * 6 + 3], d1 = rays[ray * 6 + 4], d2 = rays[ray * 6 + 5];
  float A0 = aabb[0], A1 = aabb[1], A2 = aabb[2];
  float B0 = aabb[3], B1 = aabb[4], B2 = aabb[5];
  float v0 = fabsf(d0) < 1e-6f ? 1e-6f : d0;
  float v1 = fabsf(d1) < 1e-6f ? 1e-6f : d1;
  float v2 = fabsf(d2) < 1e-6f ? 1e-6f : d2;
  float ra0 = (B0 - o0) / v0, rb0 = (A0 - o0) / v0;
  float ra1 = (B1 - o1) / v1, rb1 = (A1 - o1) / v1;
  float ra2 = (B2 - o2) / v2, rb2 = (A2 - o2) / v2;
  float tmin = fmaxf(fmaxf(fminf(ra0, rb0), fminf(ra1, rb1)), fminf(ra2, rb2));
  tmin = fmaxf(tmin, 0.05f);
  float tmax = fminf(fminf(fmaxf(ra0, rb0), fmaxf(ra1, rb1)), fmaxf(ra2, rb2));
  tmax = fmaxf(tmax, tmin + 0.001f);
  float dt = (tmax - tmin) * (1.0f / 255.0f);
  float s0 = 2.0f / (B0 - A0), s1 = 2.0f / (B1 - A1), s2 = 2.0f / (B2 - A2);

  float C = 1.0f;
  float racc = 0.f, gacc = 0.f, bacc = 0.f, wsum = 0.f, dsum = 0.f;
  for (int q = 0; q < 4; ++q) {
    int j = q * 64 + lane;
    float sfrac = (float)j * (1.0f / 255.0f);
    float z = tmin * (1.0f - sfrac) + tmax * sfrac;
    float c0 = (o0 + d0 * z - A0) * s0 - 1.0f;
    float c1 = (o1 + d1 * z - A1) * s1 - 1.0f;
    float c2 = (o2 + d2 * z - A2) * s2 - 1.0f;
    bool inside = (fabsf(c0) <= 1.0f) && (fabsf(c1) <= 1.0f) && (fabsf(c2) <= 1.0f);
    float alpha = 0.f, cr = 0.f, cg = 0.f, cb = 0.f;
    if (inside) {
      float sig = 0.f, dr = 0.f, dg = 0.f, db = 0.f;
      sig += density_orig(dplane + 0 * 1048576, dline + 0 * 4096, c0, c1, c2);
      sig += density_orig(dplane + 1 * 1048576, dline + 1 * 4096, c0, c2, c1);
      sig += density_orig(dplane + 2 * 1048576, dline + 2 * 4096, c1, c2, c0);
      app_orig(aplane + 0 * 1572864, aline + 0 * 6144,
               &bt[0 * 72 + 0], &bt[1 * 72 + 0], &bt[2 * 72 + 0],
               c0, c1, c2, dr, dg, db);
      app_orig(aplane + 1 * 1572864, aline + 1 * 6144,
               &bt[0 * 72 + 24], &bt[1 * 72 + 24], &bt[2 * 72 + 24],
               c0, c2, c1, dr, dg, db);
      app_orig(aplane + 2 * 1572864, aline + 2 * 6144,
               &bt[0 * 72 + 48], &bt[1 * 72 + 48], &bt[2 * 72 + 48],
               c1, c2, c0, dr, dg, db);
      float sp = fmaxf(sig, 0.f) + log1pf(expf(-fabsf(sig)));
      alpha = 1.0f - expf(-sp * dt);
      cr = 1.0f / (1.0f + expf(-dr));
      cg = 1.0f / (1.0f + expf(-dg));
      cb = 1.0f / (1.0f + expf(-db));
    }
    float p = 1.0f - alpha + 1e-10f;
#pragma unroll
    for (int off = 1; off < 64; off <<= 1) {
      float t = __shfl_up(p, off, 64);
      if (lane >= off) p *= t;
    }
    float tot = __shfl(p, 63, 64);
    float e = __shfl_up(p, 1, 64);
    if (lane == 0) e = 1.0f;
    float Tj = C * e;
    float w = alpha * Tj;
    racc += w * cr; gacc += w * cg; bacc += w * cb;
    wsum += w; dsum += w * z;
    C *= tot;
  }
#pragma unroll
  for (int off = 32; off > 0; off >>= 1) {
    racc += __shfl_down(racc, off, 64);
    gacc += __shfl_down(gacc, off, 64);
    bacc += __shfl_down(bacc, off, 64);
    wsum += __shfl_down(wsum, off, 64);
    dsum += __shfl_down(dsum, off, 64);
  }
  if (lane == 0) {
    float bgw = 1.0f - wsum;
    out[ray * 3 + 0] = fminf(fmaxf(racc + bgw, 0.f), 1.f);
    out[ray * 3 + 1] = fminf(fmaxf(gacc + bgw, 0.f), 1.f);
    out[ray * 3 + 2] = fminf(fmaxf(bacc + bgw, 0.f), 1.f);
    out[NRAYS * 3 + ray] = dsum;
  }
}

extern "C" void kernel_launch(void* const* d_in, const int* in_sizes, int n_in,
                              void* d_out, int out_size, void* d_ws, size_t ws_size,
                              hipStream_t stream) {
  const float* rays  = (const float*)d_in[0];
  const float* dp    = (const float*)d_in[1];
  const float* dl    = (const float*)d_in[2];
  const float* ap    = (const float*)d_in[3];
  const float* al    = (const float*)d_in[4];
  const float* basis = (const float*)d_in[5];
  const float* aabb  = (const float*)d_in[6];
  float* out = (float*)d_out;

  if (ws_size >= WS_NEED) {
    char* ws = (char*)d_ws;
    __half* dpt = (__half*)(ws + DPT_B);
    __half* dlt = (__half*)(ws + DLT_B);
    unsigned char* apt = (unsigned char*)(ws + APT_B);
    unsigned char* alt = (unsigned char*)(ws + ALT_B);
    float4* smp = (float4*)(ws + SMP_B);
    transpose_planes<<<1536, 256, 0, stream>>>(dp, ap, dpt, apt);
    transpose_lines<<<6, 256, 0, stream>>>(dl, al, dlt, alt);
    sample_kernel<<<NSAMPLES_TOT * 4 / 256, 256, 0, stream>>>(
        rays, basis, aabb, dpt, dlt, apt, alt, smp);
    scan_kernel<<<NRAYS / 4, 256, 0, stream>>>(rays, aabb, smp, out);
  } else {
    render_fallback<<<NRAYS / 4, 256, 0, stream>>>(
        rays, basis, aabb, dp, dl, ap, al, out);
  }
}

// Round 6
// 211.409 us; speedup vs baseline: 1.3362x; 1.0295x over previous
//
#include <hip/hip_runtime.h>
#include <hip/hip_fp16.h>
#include <cmath>

#define NRAYS 4096
#define NSAMP 256
#define NSAMPLES_TOT (NRAYS * NSAMP)

// Workspace layout (byte offsets), all fp16 textures channel-innermost:
//   dpt [i][y][x][16]   3*65536*16*2 = 6291456
//   dlt [i][l][16]      3*256*16*2   = 24576
//   apt [i][y][x][32]   3*65536*32*2 = 12582912  (ch24..31 zero pad)
//   alt [i][l][32]      3*256*32*2   = 49152
//   smp [ray][samp] 2xhalf2 = 8B     = 8388608
//   rayd [ray] 2xfloat4              = 131072
static constexpr size_t DPT_B = 0;
static constexpr size_t DLT_B = 6291456;
static constexpr size_t APT_B = DLT_B + 24576;       // 6316032
static constexpr size_t ALT_B = APT_B + 12582912;    // 18898944
static constexpr size_t SMP_B = ALT_B + 49152;       // 18948096
static constexpr size_t RAY_B = SMP_B + 8388608;     // 27336704
static constexpr size_t WS_NEED = RAY_B + 131072;    // 27467776 (~26.2 MiB)

typedef _Float16 __attribute__((ext_vector_type(2))) v2h;

__device__ __forceinline__ float dot2acc(__half2 a, __half2 b, float c) {
  return __builtin_amdgcn_fdot2(__builtin_bit_cast(v2h, a),
                                __builtin_bit_cast(v2h, b), c, false);
}

__device__ __forceinline__ __half2 lerp2(__half2 a, __half2 b, __half2 w) {
  return __hfma2(w, __hsub2(b, a), a);
}

// 16B load -> 4x half2
__device__ __forceinline__ void ld8h(const __half* p, __half2 h[4]) {
  uint4 r = *(const uint4*)p;
  h[0] = __builtin_bit_cast(__half2, r.x);
  h[1] = __builtin_bit_cast(__half2, r.y);
  h[2] = __builtin_bit_cast(__half2, r.z);
  h[3] = __builtin_bit_cast(__half2, r.w);
}

// 32B (two 16B loads) -> 8x half2
__device__ __forceinline__ void ld16h(const __half* p, __half2 h[8]) {
  ld8h(p, h);
  ld8h(p + 8, h + 4);
}

__device__ __forceinline__ unsigned pack2h(float a, float b) {
  return __builtin_bit_cast(unsigned, __floats2half2_rn(a, b));
}

// align_corners=True grid coord -> (i0, frac). N=256 fixed.
__device__ __forceinline__ void grid_uv(float c, int& i0, float& w) {
  float f = (c + 1.0f) * 127.5f;
  float fl = floorf(f);
  fl = fminf(fmaxf(fl, 0.0f), 254.0f);
  i0 = (int)fl;
  w = f - fl;
}

// ---------------------------------------------------------------------------
// Transpose fp32 [c][y][x] -> fp16 channel-innermost. One block per (i,y) row;
// coalesced row reads, LDS transpose, coalesced 32/64B-per-thread stores.
// blocks [0,768): density planes; [768,1536): app planes; 1536-1538 density
// lines; 1539-1541 app lines.
// ---------------------------------------------------------------------------
__global__ __launch_bounds__(256) void transpose_kernel(
    const float* __restrict__ dp, const float* __restrict__ ap,
    const float* __restrict__ dl, const float* __restrict__ al,
    __half* __restrict__ dpt, __half* __restrict__ apt,
    __half* __restrict__ dlt, __half* __restrict__ alt) {
  __shared__ float tile[24][257];
  int b = blockIdx.x, x = threadIdx.x;
  if (b < 768) {
    int i = b >> 8, y = b & 255;
    const float* src = dp + (size_t)(i * 16) * 65536 + y * 256;
#pragma unroll
    for (int c = 0; c < 16; ++c) tile[c][x] = src[c * 65536 + x];
    __syncthreads();
    float f[16];
#pragma unroll
    for (int c = 0; c < 16; ++c) f[c] = tile[c][x];
    uint4 v0, v1;
    v0.x = pack2h(f[0], f[1]);   v0.y = pack2h(f[2], f[3]);
    v0.z = pack2h(f[4], f[5]);   v0.w = pack2h(f[6], f[7]);
    v1.x = pack2h(f[8], f[9]);   v1.y = pack2h(f[10], f[11]);
    v1.z = pack2h(f[12], f[13]); v1.w = pack2h(f[14], f[15]);
    uint4* dst = (uint4*)(dpt + ((size_t)(i << 16) + (y << 8) + x) * 16);
    dst[0] = v0; dst[1] = v1;
  } else if (b < 1536) {
    int t = b - 768;
    int i = t >> 8, y = t & 255;
    const float* src = ap + (size_t)(i * 24) * 65536 + y * 256;
#pragma unroll
    for (int c = 0; c < 24; ++c) tile[c][x] = src[c * 65536 + x];
    __syncthreads();
    float f[24];
#pragma unroll
    for (int c = 0; c < 24; ++c) f[c] = tile[c][x];
    uint4 v0, v1, v2, v3;
    v0.x = pack2h(f[0], f[1]);   v0.y = pack2h(f[2], f[3]);
    v0.z = pack2h(f[4], f[5]);   v0.w = pack2h(f[6], f[7]);
    v1.x = pack2h(f[8], f[9]);   v1.y = pack2h(f[10], f[11]);
    v1.z = pack2h(f[12], f[13]); v1.w = pack2h(f[14], f[15]);
    v2.x = pack2h(f[16], f[17]); v2.y = pack2h(f[18], f[19]);
    v2.z = pack2h(f[20], f[21]); v2.w = pack2h(f[22], f[23]);
    v3.x = 0u; v3.y = 0u; v3.z = 0u; v3.w = 0u;
    uint4* dst = (uint4*)(apt + ((size_t)(i << 16) + (y << 8) + x) * 32);
    dst[0] = v0; dst[1] = v1; dst[2] = v2; dst[3] = v3;
  } else if (b < 1539) {
    int i = b - 1536, l = x;
    float f[16];
#pragma unroll
    for (int c = 0; c < 16; ++c) f[c] = dl[(i * 16 + c) * 256 + l];
    uint4 v0, v1;
    v0.x = pack2h(f[0], f[1]);   v0.y = pack2h(f[2], f[3]);
    v0.z = pack2h(f[4], f[5]);   v0.w = pack2h(f[6], f[7]);
    v1.x = pack2h(f[8], f[9]);   v1.y = pack2h(f[10], f[11]);
    v1.z = pack2h(f[12], f[13]); v1.w = pack2h(f[14], f[15]);
    uint4* dst = (uint4*)(dlt + (i * 256 + l) * 16);
    dst[0] = v0; dst[1] = v1;
  } else {
    int i = b - 1539, l = x;
    float f[24];
#pragma unroll
    for (int c = 0; c < 24; ++c) f[c] = al[(i * 24 + c) * 256 + l];
    uint4 v0, v1, v2, v3;
    v0.x = pack2h(f[0], f[1]);   v0.y = pack2h(f[2], f[3]);
    v0.z = pack2h(f[4], f[5]);   v0.w = pack2h(f[6], f[7]);
    v1.x = pack2h(f[8], f[9]);   v1.y = pack2h(f[10], f[11]);
    v1.z = pack2h(f[12], f[13]); v1.w = pack2h(f[14], f[15]);
    v2.x = pack2h(f[16], f[17]); v2.y = pack2h(f[18], f[19]);
    v2.z = pack2h(f[20], f[21]); v2.w = pack2h(f[22], f[23]);
    v3.x = 0u; v3.y = 0u; v3.z = 0u; v3.w = 0u;
    uint4* dst = (uint4*)(alt + (i * 256 + l) * 32);
    dst[0] = v0; dst[1] = v1; dst[2] = v2; dst[3] = v3;
  }
}

// ---------------------------------------------------------------------------
// Per-ray precompute: c_k(z) = p_k + q_k*z, z_j = tmin + j*dt.
// rd[ray*2]   = {p0,p1,p2,tmin}
// rd[ray*2+1] = {q0,q1,q2,dt}
// ---------------------------------------------------------------------------
__global__ __launch_bounds__(256) void ray_pre_kernel(
    const float* __restrict__ rays, const float* __restrict__ aabb,
    float4* __restrict__ rd) {
  int r = blockIdx.x * 256 + threadIdx.x;
  if (r >= NRAYS) return;
  float o0 = rays[r * 6 + 0], o1 = rays[r * 6 + 1], o2 = rays[r * 6 + 2];
  float d0 = rays[r * 6 + 3], d1 = rays[r * 6 + 4], d2 = rays[r * 6 + 5];
  float A0 = aabb[0], A1 = aabb[1], A2 = aabb[2];
  float B0 = aabb[3], B1 = aabb[4], B2 = aabb[5];
  float v0 = fabsf(d0) < 1e-6f ? 1e-6f : d0;
  float v1 = fabsf(d1) < 1e-6f ? 1e-6f : d1;
  float v2 = fabsf(d2) < 1e-6f ? 1e-6f : d2;
  float ra0 = (B0 - o0) / v0, rb0 = (A0 - o0) / v0;
  float ra1 = (B1 - o1) / v1, rb1 = (A1 - o1) / v1;
  float ra2 = (B2 - o2) / v2, rb2 = (A2 - o2) / v2;
  float tmin = fmaxf(fmaxf(fminf(ra0, rb0), fminf(ra1, rb1)), fminf(ra2, rb2));
  tmin = fmaxf(tmin, 0.05f);
  float tmax = fminf(fminf(fmaxf(ra0, rb0), fmaxf(ra1, rb1)), fmaxf(ra2, rb2));
  tmax = fmaxf(tmax, tmin + 0.001f);
  float dt = (tmax - tmin) * (1.0f / 255.0f);
  float s0 = 2.0f / (B0 - A0), s1 = 2.0f / (B1 - A1), s2 = 2.0f / (B2 - A2);
  float4 a, b;
  a.x = (o0 - A0) * s0 - 1.0f; a.y = (o1 - A1) * s1 - 1.0f;
  a.z = (o2 - A2) * s2 - 1.0f; a.w = tmin;
  b.x = d0 * s0; b.y = d1 * s1; b.z = d2 * s2; b.w = dt;
  rd[r * 2] = a;
  rd[r * 2 + 1] = b;
}

// ---------------------------------------------------------------------------
// density mode: lane sub owns 8 channels (4 half2). One 16B load per corner.
// ---------------------------------------------------------------------------
__device__ __forceinline__ float density_h2(const __half* __restrict__ pl,
                                            const __half* __restrict__ ln,
                                            int x0, __half2 wx, int y0, __half2 wy,
                                            int l0, __half2 wl, int sub,
                                            float acc) {
  const __half* p = pl + ((y0 * 256 + x0) << 4) + sub * 8;
  __half2 v00[4], v01[4], v10[4], v11[4], la[4], lb[4];
  ld8h(p, v00);
  ld8h(p + 16, v01);
  ld8h(p + 4096, v10);
  ld8h(p + 4096 + 16, v11);
  const __half* lp = ln + (l0 << 4) + sub * 8;
  ld8h(lp, la);
  ld8h(lp + 16, lb);
#pragma unroll
  for (int r = 0; r < 4; ++r) {
    __half2 m = lerp2(lerp2(v00[r], v01[r], wx), lerp2(v10[r], v11[r], wx), wy);
    __half2 l = lerp2(la[r], lb[r], wl);
    acc = dot2acc(m, l, acc);
  }
  return acc;
}

// ---------------------------------------------------------------------------
// app mode: lane sub owns 16 channels (8 half2, incl zero pad). 2x16B loads
// per corner. Basis rows (half2, LDS) dotted on the fly.
// ---------------------------------------------------------------------------
__device__ __forceinline__ void app_h2(const __half* __restrict__ pl,
                                       const __half* __restrict__ ln,
                                       const __half2* __restrict__ btR,
                                       const __half2* __restrict__ btG,
                                       const __half2* __restrict__ btB,
                                       int x0, __half2 wx, int y0, __half2 wy,
                                       int l0, __half2 wl, int sub,
                                       float& dr, float& dg, float& db) {
  const __half* p = pl + ((size_t)(y0 * 256 + x0) << 5) + sub * 16;
  __half2 A[8], B[8], C[8], D[8], LA[8], LB[8];
  ld16h(p, A);
  ld16h(p + 32, B);
  ld16h(p + 8192, C);
  ld16h(p + 8192 + 32, D);
  const __half* lp = ln + (l0 << 5) + sub * 16;
  ld16h(lp, LA);
  ld16h(lp + 32, LB);
#pragma unroll
  for (int r = 0; r < 8; ++r) {
    __half2 m = lerp2(lerp2(A[r], B[r], wx), lerp2(C[r], D[r], wx), wy);
    __half2 l = lerp2(LA[r], LB[r], wl);
    __half2 av = __hmul2(m, l);
    dr = dot2acc(av, btR[r], dr);
    dg = dot2acc(av, btG[r], dg);
    db = dot2acc(av, btB[r], db);
  }
}

// ---------------------------------------------------------------------------
// Sample kernel: 2 lanes per sample; block = 128 samples of one ray (ray is
// block-uniform -> scalar ray data). 8192 blocks x 256 threads.
// ---------------------------------------------------------------------------
__global__ __launch_bounds__(256) void sample_kernel(
    const float4* __restrict__ rd, const float* __restrict__ basis,
    const __half* __restrict__ dpt, const __half* __restrict__ dlt,
    const __half* __restrict__ apt, const __half* __restrict__ alt,
    uint2* __restrict__ smp) {
  __shared__ __align__(16) __half bth[3][3][32];  // [k][mode][ch], pad zeroed
  int tid = threadIdx.x;
  // 288 entries > 256 threads: MUST stride-loop (round-5 bug: bth[2][2][*]
  // was left uninitialized -> blue channel garbage).
  for (int t = tid; t < 288; t += 256) {
    int k = t / 96, rem = t - k * 96;
    int m = rem >> 5, c = rem & 31;
    float v = (c < 24) ? basis[(m * 24 + c) * 3 + k] : 0.0f;
    bth[k][m][c] = __float2half(v);
  }
  __syncthreads();

  int ray = blockIdx.x >> 1;
  int j = ((blockIdx.x & 1) << 7) + (tid >> 1);
  int sub = tid & 1;

  float4 ra = rd[ray * 2];
  float4 rb = rd[ray * 2 + 1];
  float z = fmaf((float)j, rb.w, ra.w);
  float c0 = fmaf(rb.x, z, ra.x);
  float c1 = fmaf(rb.y, z, ra.y);
  float c2 = fmaf(rb.z, z, ra.z);
  bool inside = (fabsf(c0) <= 1.0f) && (fabsf(c1) <= 1.0f) && (fabsf(c2) <= 1.0f);

  float sig = 0.f, dr = 0.f, dg = 0.f, db = 0.f;
  if (inside) {
    int i0, i1, i2;
    float w0, w1, w2;
    grid_uv(c0, i0, w0);
    grid_uv(c1, i1, w1);
    grid_uv(c2, i2, w2);
    __half2 h0 = __float2half2_rn(w0);
    __half2 h1 = __float2half2_rn(w1);
    __half2 h2 = __float2half2_rn(w2);
    // MAT_MODE = [(0,1),(0,2),(1,2)], VEC_MODE = [2,1,0]
    sig = density_h2(dpt + 0 * 1048576, dlt + 0 * 4096, i0, h0, i1, h1, i2, h2, sub, sig);
    sig = density_h2(dpt + 1 * 1048576, dlt + 1 * 4096, i0, h0, i2, h2, i1, h1, sub, sig);
    sig = density_h2(dpt + 2 * 1048576, dlt + 2 * 4096, i1, h1, i2, h2, i0, h0, sub, sig);
    app_h2(apt + 0 * 2097152, alt + 0 * 8192,
           (const __half2*)&bth[0][0][sub * 16], (const __half2*)&bth[1][0][sub * 16],
           (const __half2*)&bth[2][0][sub * 16], i0, h0, i1, h1, i2, h2, sub, dr, dg, db);
    app_h2(apt + 1 * 2097152, alt + 1 * 8192,
           (const __half2*)&bth[0][1][sub * 16], (const __half2*)&bth[1][1][sub * 16],
           (const __half2*)&bth[2][1][sub * 16], i0, h0, i2, h2, i1, h1, sub, dr, dg, db);
    app_h2(apt + 2 * 2097152, alt + 2 * 8192,
           (const __half2*)&bth[0][2][sub * 16], (const __half2*)&bth[1][2][sub * 16],
           (const __half2*)&bth[2][2][sub * 16], i1, h1, i2, h2, i0, h0, sub, dr, dg, db);
  }
  // reduce over the 2-lane group
  sig += __shfl_xor(sig, 1, 64);
  dr += __shfl_xor(dr, 1, 64);
  dg += __shfl_xor(dg, 1, 64);
  db += __shfl_xor(db, 1, 64);

  if (sub == 0) {
    float sp = fmaxf(sig, 0.f) + log1pf(expf(-fabsf(sig)));  // softplus
    float alpha = inside ? (1.0f - expf(-sp * rb.w)) : 0.0f;
    float cr = 1.0f / (1.0f + expf(-dr));
    float cg = 1.0f / (1.0f + expf(-dg));
    float cb = 1.0f / (1.0f + expf(-db));
    uint2 sv;
    sv.x = pack2h(alpha, cr);
    sv.y = pack2h(cg, cb);
    smp[ray * 256 + j] = sv;
  }
}

// ---------------------------------------------------------------------------
// Scan kernel: per-ray transmittance scan + composite. One wave per ray.
// ---------------------------------------------------------------------------
__global__ __launch_bounds__(256) void scan_kernel(
    const float4* __restrict__ rd, const uint2* __restrict__ smp,
    float* __restrict__ out) {
  int tid = threadIdx.x;
  int lane = tid & 63;
  int ray = blockIdx.x * 4 + (tid >> 6);

  float tmin = rd[ray * 2].w;
  float dt = rd[ray * 2 + 1].w;

  float C = 1.0f;
  float racc = 0.f, gacc = 0.f, bacc = 0.f, wsum = 0.f, dsum = 0.f;

  for (int q = 0; q < 4; ++q) {
    int j = q * 64 + lane;
    uint2 sv = smp[ray * 256 + j];
    float2 ar = __half22float2(__builtin_bit_cast(__half2, sv.x));
    float2 gb = __half22float2(__builtin_bit_cast(__half2, sv.y));
    float alpha = ar.x;
    float z = fmaf((float)j, dt, tmin);

    float p = 1.0f - alpha + 1e-10f;
#pragma unroll
    for (int off = 1; off < 64; off <<= 1) {
      float t = __shfl_up(p, off, 64);
      if (lane >= off) p *= t;
    }
    float tot = __shfl(p, 63, 64);
    float e = __shfl_up(p, 1, 64);
    if (lane == 0) e = 1.0f;
    float Tj = C * e;
    float w = alpha * Tj;
    racc += w * ar.y;
    gacc += w * gb.x;
    bacc += w * gb.y;
    wsum += w;
    dsum += w * z;
    C *= tot;
  }

#pragma unroll
  for (int off = 32; off > 0; off >>= 1) {
    racc += __shfl_down(racc, off, 64);
    gacc += __shfl_down(gacc, off, 64);
    bacc += __shfl_down(bacc, off, 64);
    wsum += __shfl_down(wsum, off, 64);
    dsum += __shfl_down(dsum, off, 64);
  }
  if (lane == 0) {
    float bgw = 1.0f - wsum;  // WHITE_BG
    out[ray * 3 + 0] = fminf(fmaxf(racc + bgw, 0.f), 1.f);
    out[ray * 3 + 1] = fminf(fmaxf(gacc + bgw, 0.f), 1.f);
    out[ray * 3 + 2] = fminf(fmaxf(bacc + bgw, 0.f), 1.f);
    out[NRAYS * 3 + ray] = dsum;
  }
}

// ---------------------------------------------------------------------------
// Fallback (ws too small): single-kernel fp32 render on original layout.
// ---------------------------------------------------------------------------
__device__ __forceinline__ float density_orig(const float* __restrict__ plane,
                                              const float* __restrict__ line,
                                              float cx, float cy, float cw) {
  int x0, y0, l0; float wx, wy, wl;
  grid_uv(cx, x0, wx); grid_uv(cy, y0, wy); grid_uv(cw, l0, wl);
  int base = y0 * 256 + x0;
  float s = 0.0f;
#pragma unroll 4
  for (int c = 0; c < 16; ++c) {
    const float* pc = plane + c * 65536;
    float v00 = pc[base], v01 = pc[base + 1];
    float v10 = pc[base + 256], v11 = pc[base + 257];
    float top = fmaf(wx, v01 - v00, v00);
    float bot = fmaf(wx, v11 - v10, v10);
    float mid = fmaf(wy, bot - top, top);
    float la = line[c * 256 + l0], lb = line[c * 256 + l0 + 1];
    float lv = fmaf(wl, lb - la, la);
    s += mid * lv;
  }
  return s;
}

__device__ __forceinline__ void app_orig(const float* __restrict__ plane,
                                         const float* __restrict__ line,
                                         const float* __restrict__ btR,
                                         const float* __restrict__ btG,
                                         const float* __restrict__ btB,
                                         float cx, float cy, float cw,
                                         float& dr, float& dg, float& db) {
  int x0, y0, l0; float wx, wy, wl;
  grid_uv(cx, x0, wx); grid_uv(cy, y0, wy); grid_uv(cw, l0, wl);
  int base = y0 * 256 + x0;
#pragma unroll 4
  for (int c = 0; c < 24; ++c) {
    const float* pc = plane + c * 65536;
    float v00 = pc[base], v01 = pc[base + 1];
    float v10 = pc[base + 256], v11 = pc[base + 257];
    float top = fmaf(wx, v01 - v00, v00);
    float bot = fmaf(wx, v11 - v10, v10);
    float mid = fmaf(wy, bot - top, top);
    float la = line[c * 256 + l0], lb = line[c * 256 + l0 + 1];
    float lv = fmaf(wl, lb - la, la);
    float av = mid * lv;
    dr += av * btR[c]; dg += av * btG[c]; db += av * btB[c];
  }
}

__global__ __launch_bounds__(256) void render_fallback(
    const float* __restrict__ rays, const float* __restrict__ basis,
    const float* __restrict__ aabb, const float* __restrict__ dplane,
    const float* __restrict__ dline, const float* __restrict__ aplane,
    const float* __restrict__ aline, float* __restrict__ out) {
  __shared__ float bt[3 * 72];
  int tid = threadIdx.x;
  if (tid < 216) {
    int k = tid / 72, r = tid - k * 72;
    bt[tid] = basis[r * 3 + k];
  }
  __syncthreads();
  int lane = tid & 63;
  int ray = blockIdx.x * 4 + (tid >> 6);

  float o0 = rays[ray * 6 + 0], o1 = rays[ray * 6 + 1], o2 = rays[ray * 6 + 2];
  float d0 = rays[ray * 6 + 3], d1 = rays[ray * 6 + 4], d2 = rays[ray * 6 + 5];
  float A0 = aabb[0], A1 = aabb[1], A2 = aabb[2];
  float B0 = aabb[3], B1 = aabb[4], B2 = aabb[5];
  float v0 = fabsf(d0) < 1e-6f ? 1e-6f : d0;
  float v1 = fabsf(d1) < 1e-6f ? 1e-6f : d1;
  float v2 = fabsf(d2) < 1e-6f ? 1e-6f : d2;
  float ra0 = (B0 - o0) / v0, rb0 = (A0 - o0) / v0;
  float ra1 = (B1 - o1) / v1, rb1 = (A1 - o1) / v1;
  float ra2 = (B2 - o2) / v2, rb2 = (A2 - o2) / v2;
  float tmin = fmaxf(fmaxf(fminf(ra0, rb0), fminf(ra1, rb1)), fminf(ra2, rb2));
  tmin = fmaxf(tmin, 0.05f);
  float tmax = fminf(fminf(fmaxf(ra0, rb0), fmaxf(ra1, rb1)), fmaxf(ra2, rb2));
  tmax = fmaxf(tmax, tmin + 0.001f);
  float dt = (tmax - tmin) * (1.0f / 255.0f);
  float s0 = 2.0f / (B0 - A0), s1 = 2.0f / (B1 - A1), s2 = 2.0f / (B2 - A2);

  float C = 1.0f;
  float racc = 0.f, gacc = 0.f, bacc = 0.f, wsum = 0.f, dsum = 0.f;
  for (int q = 0; q < 4; ++q) {
    int j = q * 64 + lane;
    float sfrac = (float)j * (1.0f / 255.0f);
    float z = tmin * (1.0f - sfrac) + tmax * sfrac;
    float c0 = (o0 + d0 * z - A0) * s0 - 1.0f;
    float c1 = (o1 + d1 * z - A1) * s1 - 1.0f;
    float c2 = (o2 + d2 * z - A2) * s2 - 1.0f;
    bool inside = (fabsf(c0) <= 1.0f) && (fabsf(c1) <= 1.0f) && (fabsf(c2) <= 1.0f);
    float alpha = 0.f, cr = 0.f, cg = 0.f, cb = 0.f;
    if (inside) {
      float sig = 0.f, dr = 0.f, dg = 0.f, db = 0.f;
      sig += density_orig(dplane + 0 * 1048576, dline + 0 * 4096, c0, c1, c2);
      sig += density_orig(dplane + 1 * 1048576, dline + 1 * 4096, c0, c2, c1);
      sig += density_orig(dplane + 2 * 1048576, dline + 2 * 4096, c1, c2, c0);
      app_orig(aplane + 0 * 1572864, aline + 0 * 6144,
               &bt[0 * 72 + 0], &bt[1 * 72 + 0], &bt[2 * 72 + 0],
               c0, c1, c2, dr, dg, db);
      app_orig(aplane + 1 * 1572864, aline + 1 * 6144,
               &bt[0 * 72 + 24], &bt[1 * 72 + 24], &bt[2 * 72 + 24],
               c0, c2, c1, dr, dg, db);
      app_orig(aplane + 2 * 1572864, aline + 2 * 6144,
               &bt[0 * 72 + 48], &bt[1 * 72 + 48], &bt[2 * 72 + 48],
               c1, c2, c0, dr, dg, db);
      float sp = fmaxf(sig, 0.f) + log1pf(expf(-fabsf(sig)));
      alpha = 1.0f - expf(-sp * dt);
      cr = 1.0f / (1.0f + expf(-dr));
      cg = 1.0f / (1.0f + expf(-dg));
      cb = 1.0f / (1.0f + expf(-db));
    }
    float p = 1.0f - alpha + 1e-10f;
#pragma unroll
    for (int off = 1; off < 64; off <<= 1) {
      float t = __shfl_up(p, off, 64);
      if (lane >= off) p *= t;
    }
    float tot = __shfl(p, 63, 64);
    float e = __shfl_up(p, 1, 64);
    if (lane == 0) e = 1.0f;
    float Tj = C * e;
    float w = alpha * Tj;
    racc += w * cr; gacc += w * cg; bacc += w * cb;
    wsum += w; dsum += w * z;
    C *= tot;
  }
#pragma unroll
  for (int off = 32; off > 0; off >>= 1) {
    racc += __shfl_down(racc, off, 64);
    gacc += __shfl_down(gacc, off, 64);
    bacc += __shfl_down(bacc, off, 64);
    wsum += __shfl_down(wsum, off, 64);
    dsum += __shfl_down(dsum, off, 64);
  }
  if (lane == 0) {
    float bgw = 1.0f - wsum;
    out[ray * 3 + 0] = fminf(fmaxf(racc + bgw, 0.f), 1.f);
    out[ray * 3 + 1] = fminf(fmaxf(gacc + bgw, 0.f), 1.f);
    out[ray * 3 + 2] = fminf(fmaxf(bacc + bgw, 0.f), 1.f);
    out[NRAYS * 3 + ray] = dsum;
  }
}

extern "C" void kernel_launch(void* const* d_in, const int* in_sizes, int n_in,
                              void* d_out, int out_size, void* d_ws, size_t ws_size,
                              hipStream_t stream) {
  const float* rays  = (const float*)d_in[0];
  const float* dp    = (const float*)d_in[1];
  const float* dl    = (const float*)d_in[2];
  const float* ap    = (const float*)d_in[3];
  const float* al    = (const float*)d_in[4];
  const float* basis = (const float*)d_in[5];
  const float* aabb  = (const float*)d_in[6];
  float* out = (float*)d_out;

  if (ws_size >= WS_NEED) {
    char* ws = (char*)d_ws;
    __half* dpt = (__half*)(ws + DPT_B);
    __half* dlt = (__half*)(ws + DLT_B);
    __half* apt = (__half*)(ws + APT_B);
    __half* alt = (__half*)(ws + ALT_B);
    uint2* smp = (uint2*)(ws + SMP_B);
    float4* rayd = (float4*)(ws + RAY_B);
    transpose_kernel<<<1542, 256, 0, stream>>>(dp, ap, dl, al, dpt, apt, dlt, alt);
    ray_pre_kernel<<<16, 256, 0, stream>>>(rays, aabb, rayd);
    sample_kernel<<<NRAYS * 2, 256, 0, stream>>>(rayd, basis, dpt, dlt, apt, alt, smp);
    scan_kernel<<<NRAYS / 4, 256, 0, stream>>>(rayd, smp, out);
  } else {
    render_fallback<<<NRAYS / 4, 256, 0, stream>>>(
        rays, basis, aabb, dp, dl, ap, al, out);
  }
}

// Round 7
// 171.158 us; speedup vs baseline: 1.6504x; 1.2352x over previous
//
#include <hip/hip_runtime.h>
#include <hip/hip_fp16.h>
#include <cmath>

#define NRAYS 4096
#define NSAMP 256
#define NSAMPLES_TOT (NRAYS * NSAMP)

// Workspace layout (byte offsets):
//   dpt fp16 [i][y][x][16]   3*65536*16*2 = 6291456
//   dlt fp16 [i][l][16]      3*256*16*2   = 24576
//   apt fp8  [i][y][x][32]   3*65536*32   = 6291456   (ch24..31 zero pad)
//   alt fp8  [i][l][32]      3*256*32     = 24576
//   smp [ray][samp] 2xhalf2 = 8B          = 8388608
//   rayd [ray] 2xfloat4                   = 131072
static constexpr size_t DPT_B = 0;
static constexpr size_t DLT_B = 6291456;
static constexpr size_t APT_B = DLT_B + 24576;      // 6316032
static constexpr size_t ALT_B = APT_B + 6291456;    // 12607488
static constexpr size_t SMP_B = ALT_B + 24576;      // 12632064
static constexpr size_t RAY_B = SMP_B + 8388608;    // 21020672
static constexpr size_t WS_NEED = RAY_B + 131072;   // 21151744 (~20.2 MiB)

typedef _Float16 __attribute__((ext_vector_type(2))) v2h;
typedef __attribute__((ext_vector_type(2))) float f32x2;

__device__ __forceinline__ float dot2acc(__half2 a, __half2 b, float c) {
  return __builtin_amdgcn_fdot2(__builtin_bit_cast(v2h, a),
                                __builtin_bit_cast(v2h, b), c, false);
}

__device__ __forceinline__ __half2 lerp2(__half2 a, __half2 b, __half2 w) {
  return __hfma2(w, __hsub2(b, a), a);
}

// 16B load -> 4x half2
__device__ __forceinline__ void ld8h(const __half* p, __half2 h[4]) {
  uint4 r = *(const uint4*)p;
  h[0] = __builtin_bit_cast(__half2, r.x);
  h[1] = __builtin_bit_cast(__half2, r.y);
  h[2] = __builtin_bit_cast(__half2, r.z);
  h[3] = __builtin_bit_cast(__half2, r.w);
}

__device__ __forceinline__ unsigned pack2h(float a, float b) {
  return __builtin_bit_cast(unsigned, __floats2half2_rn(a, b));
}

// dword of 4 fp8(e4m3) -> 2x half2 (HW cvt + pack)
__device__ __forceinline__ void dec4f8h(unsigned w, __half2& h0, __half2& h1) {
  f32x2 lo = __builtin_amdgcn_cvt_pk_f32_fp8((int)w, false);
  f32x2 hi = __builtin_amdgcn_cvt_pk_f32_fp8((int)w, true);
  h0 = __floats2half2_rn(lo.x, lo.y);
  h1 = __floats2half2_rn(hi.x, hi.y);
}

// 16 fp8 bytes (uint4) -> 8x half2
__device__ __forceinline__ void dec16f8(uint4 q, __half2 h[8]) {
  dec4f8h(q.x, h[0], h[1]);
  dec4f8h(q.y, h[2], h[3]);
  dec4f8h(q.z, h[4], h[5]);
  dec4f8h(q.w, h[6], h[7]);
}

// 4 floats -> dword of 4 fp8(e4m3)
__device__ __forceinline__ unsigned pk4f8(float a, float b, float c, float d) {
  int w = __builtin_amdgcn_cvt_pk_fp8_f32(a, b, 0, false);
  w = __builtin_amdgcn_cvt_pk_fp8_f32(c, d, w, true);
  return (unsigned)w;
}

// align_corners=True grid coord -> (i0, frac). N=256 fixed.
__device__ __forceinline__ void grid_uv(float c, int& i0, float& w) {
  float f = (c + 1.0f) * 127.5f;
  float fl = floorf(f);
  fl = fminf(fmaxf(fl, 0.0f), 254.0f);
  i0 = (int)fl;
  w = f - fl;
}

// ---------------------------------------------------------------------------
// Prep kernel: texture transpose (+dtype cast) AND per-ray precompute.
// blocks [0,768): density planes fp16; [768,1536): app planes fp8;
// 1536-1538 density lines; 1539-1541 app lines; [1542,1558): ray precompute.
// Plane rows: coalesced reads, LDS transpose, coalesced vector stores.
// ---------------------------------------------------------------------------
__global__ __launch_bounds__(256) void prep_kernel(
    const float* __restrict__ dp, const float* __restrict__ ap,
    const float* __restrict__ dl, const float* __restrict__ al,
    const float* __restrict__ rays, const float* __restrict__ aabb,
    __half* __restrict__ dpt, unsigned char* __restrict__ apt,
    __half* __restrict__ dlt, unsigned char* __restrict__ alt,
    float4* __restrict__ rd) {
  __shared__ float tile[24][257];
  int b = blockIdx.x, x = threadIdx.x;
  if (b < 768) {
    int i = b >> 8, y = b & 255;
    const float* src = dp + (size_t)(i * 16) * 65536 + y * 256;
#pragma unroll
    for (int c = 0; c < 16; ++c) tile[c][x] = src[c * 65536 + x];
    __syncthreads();
    float f[16];
#pragma unroll
    for (int c = 0; c < 16; ++c) f[c] = tile[c][x];
    uint4 v0, v1;
    v0.x = pack2h(f[0], f[1]);   v0.y = pack2h(f[2], f[3]);
    v0.z = pack2h(f[4], f[5]);   v0.w = pack2h(f[6], f[7]);
    v1.x = pack2h(f[8], f[9]);   v1.y = pack2h(f[10], f[11]);
    v1.z = pack2h(f[12], f[13]); v1.w = pack2h(f[14], f[15]);
    uint4* dst = (uint4*)(dpt + ((size_t)(i << 16) + (y << 8) + x) * 16);
    dst[0] = v0; dst[1] = v1;
  } else if (b < 1536) {
    int t = b - 768;
    int i = t >> 8, y = t & 255;
    const float* src = ap + (size_t)(i * 24) * 65536 + y * 256;
#pragma unroll
    for (int c = 0; c < 24; ++c) tile[c][x] = src[c * 65536 + x];
    __syncthreads();
    float f[24];
#pragma unroll
    for (int c = 0; c < 24; ++c) f[c] = tile[c][x];
    uint4 v0, v1;
    v0.x = pk4f8(f[0], f[1], f[2], f[3]);
    v0.y = pk4f8(f[4], f[5], f[6], f[7]);
    v0.z = pk4f8(f[8], f[9], f[10], f[11]);
    v0.w = pk4f8(f[12], f[13], f[14], f[15]);
    v1.x = pk4f8(f[16], f[17], f[18], f[19]);
    v1.y = pk4f8(f[20], f[21], f[22], f[23]);
    v1.z = 0u; v1.w = 0u;
    uint4* dst = (uint4*)(apt + ((size_t)(i << 16) + (y << 8) + x) * 32);
    dst[0] = v0; dst[1] = v1;
  } else if (b < 1539) {
    int i = b - 1536, l = x;
    float f[16];
#pragma unroll
    for (int c = 0; c < 16; ++c) f[c] = dl[(i * 16 + c) * 256 + l];
    uint4 v0, v1;
    v0.x = pack2h(f[0], f[1]);   v0.y = pack2h(f[2], f[3]);
    v0.z = pack2h(f[4], f[5]);   v0.w = pack2h(f[6], f[7]);
    v1.x = pack2h(f[8], f[9]);   v1.y = pack2h(f[10], f[11]);
    v1.z = pack2h(f[12], f[13]); v1.w = pack2h(f[14], f[15]);
    uint4* dst = (uint4*)(dlt + (i * 256 + l) * 16);
    dst[0] = v0; dst[1] = v1;
  } else if (b < 1542) {
    int i = b - 1539, l = x;
    float f[24];
#pragma unroll
    for (int c = 0; c < 24; ++c) f[c] = al[(i * 24 + c) * 256 + l];
    uint4 v0, v1;
    v0.x = pk4f8(f[0], f[1], f[2], f[3]);
    v0.y = pk4f8(f[4], f[5], f[6], f[7]);
    v0.z = pk4f8(f[8], f[9], f[10], f[11]);
    v0.w = pk4f8(f[12], f[13], f[14], f[15]);
    v1.x = pk4f8(f[16], f[17], f[18], f[19]);
    v1.y = pk4f8(f[20], f[21], f[22], f[23]);
    v1.z = 0u; v1.w = 0u;
    uint4* dst = (uint4*)(alt + (i * 256 + l) * 32);
    dst[0] = v0; dst[1] = v1;
  } else {
    int r = (b - 1542) * 256 + x;
    if (r < NRAYS) {
      float o0 = rays[r * 6 + 0], o1 = rays[r * 6 + 1], o2 = rays[r * 6 + 2];
      float d0 = rays[r * 6 + 3], d1 = rays[r * 6 + 4], d2 = rays[r * 6 + 5];
      float A0 = aabb[0], A1 = aabb[1], A2 = aabb[2];
      float B0 = aabb[3], B1 = aabb[4], B2 = aabb[5];
      float v0 = fabsf(d0) < 1e-6f ? 1e-6f : d0;
      float v1 = fabsf(d1) < 1e-6f ? 1e-6f : d1;
      float v2 = fabsf(d2) < 1e-6f ? 1e-6f : d2;
      float ra0 = (B0 - o0) / v0, rb0 = (A0 - o0) / v0;
      float ra1 = (B1 - o1) / v1, rb1 = (A1 - o1) / v1;
      float ra2 = (B2 - o2) / v2, rb2 = (A2 - o2) / v2;
      float tmin = fmaxf(fmaxf(fminf(ra0, rb0), fminf(ra1, rb1)), fminf(ra2, rb2));
      tmin = fmaxf(tmin, 0.05f);
      float tmax = fminf(fminf(fmaxf(ra0, rb0), fmaxf(ra1, rb1)), fmaxf(ra2, rb2));
      tmax = fmaxf(tmax, tmin + 0.001f);
      float dt = (tmax - tmin) * (1.0f / 255.0f);
      float s0 = 2.0f / (B0 - A0), s1 = 2.0f / (B1 - A1), s2 = 2.0f / (B2 - A2);
      float4 a2, b2;
      a2.x = (o0 - A0) * s0 - 1.0f; a2.y = (o1 - A1) * s1 - 1.0f;
      a2.z = (o2 - A2) * s2 - 1.0f; a2.w = tmin;
      b2.x = d0 * s0; b2.y = d1 * s1; b2.z = d2 * s2; b2.w = dt;
      rd[r * 2] = a2;
      rd[r * 2 + 1] = b2;
    }
  }
}

// ---------------------------------------------------------------------------
// density mode (fp16): lane sub owns 8 channels (4 half2). 16B loads.
// ---------------------------------------------------------------------------
__device__ __forceinline__ float density_h2(const __half* __restrict__ pl,
                                            const __half* __restrict__ ln,
                                            int x0, __half2 wx, int y0, __half2 wy,
                                            int l0, __half2 wl, int sub,
                                            float acc) {
  const __half* p = pl + ((y0 * 256 + x0) << 4) + sub * 8;
  __half2 v00[4], v01[4], v10[4], v11[4], la[4], lb[4];
  ld8h(p, v00);
  ld8h(p + 16, v01);
  ld8h(p + 4096, v10);
  ld8h(p + 4096 + 16, v11);
  const __half* lp = ln + (l0 << 4) + sub * 8;
  ld8h(lp, la);
  ld8h(lp + 16, lb);
#pragma unroll
  for (int r = 0; r < 4; ++r) {
    __half2 m = lerp2(lerp2(v00[r], v01[r], wx), lerp2(v10[r], v11[r], wx), wy);
    __half2 l = lerp2(la[r], lb[r], wl);
    acc = dot2acc(m, l, acc);
  }
  return acc;
}

// ---------------------------------------------------------------------------
// app mode (fp8 storage, fp16 math): lane sub owns 16 padded channels.
// One 16B load per corner, HW fp8->f32 cvt + pack to half2.
// ---------------------------------------------------------------------------
__device__ __forceinline__ void app_f8(const unsigned char* __restrict__ pl,
                                       const unsigned char* __restrict__ ln,
                                       const __half2* __restrict__ btR,
                                       const __half2* __restrict__ btG,
                                       const __half2* __restrict__ btB,
                                       int x0, __half2 wx, int y0, __half2 wy,
                                       int l0, __half2 wl, int sub,
                                       float& dr, float& dg, float& db) {
  const unsigned char* p = pl + (size_t)((y0 * 256 + x0) << 5) + sub * 16;
  uint4 qA = *(const uint4*)p;
  uint4 qB = *(const uint4*)(p + 32);
  uint4 qC = *(const uint4*)(p + 8192);
  uint4 qD = *(const uint4*)(p + 8192 + 32);
  const unsigned char* lp = ln + (l0 << 5) + sub * 16;
  uint4 qLA = *(const uint4*)lp;
  uint4 qLB = *(const uint4*)(lp + 32);
  __half2 A[8], B[8], C[8], D[8], LA[8], LB[8];
  dec16f8(qA, A);
  dec16f8(qB, B);
  dec16f8(qC, C);
  dec16f8(qD, D);
  dec16f8(qLA, LA);
  dec16f8(qLB, LB);
#pragma unroll
  for (int r = 0; r < 8; ++r) {
    __half2 m = lerp2(lerp2(A[r], B[r], wx), lerp2(C[r], D[r], wx), wy);
    __half2 l = lerp2(LA[r], LB[r], wl);
    __half2 av = __hmul2(m, l);
    dr = dot2acc(av, btR[r], dr);
    dg = dot2acc(av, btG[r], dg);
    db = dot2acc(av, btB[r], db);
  }
}

// ---------------------------------------------------------------------------
// Sample kernel: 2 lanes per sample; block = 128 samples of one ray.
// 8192 blocks x 256 threads.
// ---------------------------------------------------------------------------
__global__ __launch_bounds__(256) void sample_kernel(
    const float4* __restrict__ rd, const float* __restrict__ basis,
    const __half* __restrict__ dpt, const __half* __restrict__ dlt,
    const unsigned char* __restrict__ apt, const unsigned char* __restrict__ alt,
    uint2* __restrict__ smp) {
  __shared__ __align__(16) __half bth[3][3][32];  // [k][mode][ch], pad zeroed
  int tid = threadIdx.x;
  // 288 entries > 256 threads: stride-loop (r5 bug: tail was uninitialized).
  for (int t = tid; t < 288; t += 256) {
    int k = t / 96, rem = t - k * 96;
    int m = rem >> 5, c = rem & 31;
    float v = (c < 24) ? basis[(m * 24 + c) * 3 + k] : 0.0f;
    bth[k][m][c] = __float2half(v);
  }
  __syncthreads();

  int ray = blockIdx.x >> 1;
  int j = ((blockIdx.x & 1) << 7) + (tid >> 1);
  int sub = tid & 1;

  float4 ra = rd[ray * 2];
  float4 rb = rd[ray * 2 + 1];
  float z = fmaf((float)j, rb.w, ra.w);
  float c0 = fmaf(rb.x, z, ra.x);
  float c1 = fmaf(rb.y, z, ra.y);
  float c2 = fmaf(rb.z, z, ra.z);
  bool inside = (fabsf(c0) <= 1.0f) && (fabsf(c1) <= 1.0f) && (fabsf(c2) <= 1.0f);

  float sig = 0.f, dr = 0.f, dg = 0.f, db = 0.f;
  if (inside) {
    int i0, i1, i2;
    float w0, w1, w2;
    grid_uv(c0, i0, w0);
    grid_uv(c1, i1, w1);
    grid_uv(c2, i2, w2);
    __half2 h0 = __float2half2_rn(w0);
    __half2 h1 = __float2half2_rn(w1);
    __half2 h2 = __float2half2_rn(w2);
    // MAT_MODE = [(0,1),(0,2),(1,2)], VEC_MODE = [2,1,0]
    sig = density_h2(dpt + 0 * 1048576, dlt + 0 * 4096, i0, h0, i1, h1, i2, h2, sub, sig);
    sig = density_h2(dpt + 1 * 1048576, dlt + 1 * 4096, i0, h0, i2, h2, i1, h1, sub, sig);
    sig = density_h2(dpt + 2 * 1048576, dlt + 2 * 4096, i1, h1, i2, h2, i0, h0, sub, sig);
    app_f8(apt + 0 * 2097152, alt + 0 * 8192,
           (const __half2*)&bth[0][0][sub * 16], (const __half2*)&bth[1][0][sub * 16],
           (const __half2*)&bth[2][0][sub * 16], i0, h0, i1, h1, i2, h2, sub, dr, dg, db);
    app_f8(apt + 1 * 2097152, alt + 1 * 8192,
           (const __half2*)&bth[0][1][sub * 16], (const __half2*)&bth[1][1][sub * 16],
           (const __half2*)&bth[2][1][sub * 16], i0, h0, i2, h2, i1, h1, sub, dr, dg, db);
    app_f8(apt + 2 * 2097152, alt + 2 * 8192,
           (const __half2*)&bth[0][2][sub * 16], (const __half2*)&bth[1][2][sub * 16],
           (const __half2*)&bth[2][2][sub * 16], i1, h1, i2, h2, i0, h0, sub, dr, dg, db);
  }
  // reduce over the 2-lane group
  sig += __shfl_xor(sig, 1, 64);
  dr += __shfl_xor(dr, 1, 64);
  dg += __shfl_xor(dg, 1, 64);
  db += __shfl_xor(db, 1, 64);

  if (sub == 0) {
    float sp = fmaxf(sig, 0.f) + log1pf(expf(-fabsf(sig)));  // softplus
    float alpha = inside ? (1.0f - expf(-sp * rb.w)) : 0.0f;
    float cr = 1.0f / (1.0f + expf(-dr));
    float cg = 1.0f / (1.0f + expf(-dg));
    float cb = 1.0f / (1.0f + expf(-db));
    uint2 sv;
    sv.x = pack2h(alpha, cr);
    sv.y = pack2h(cg, cb);
    smp[ray * 256 + j] = sv;
  }
}

// ---------------------------------------------------------------------------
// Scan kernel: per-ray transmittance scan + composite. One wave per ray.
// ---------------------------------------------------------------------------
__global__ __launch_bounds__(256) void scan_kernel(
    const float4* __restrict__ rd, const uint2* __restrict__ smp,
    float* __restrict__ out) {
  int tid = threadIdx.x;
  int lane = tid & 63;
  int ray = blockIdx.x * 4 + (tid >> 6);

  float tmin = rd[ray * 2].w;
  float dt = rd[ray * 2 + 1].w;

  float C = 1.0f;
  float racc = 0.f, gacc = 0.f, bacc = 0.f, wsum = 0.f, dsum = 0.f;

  for (int q = 0; q < 4; ++q) {
    int j = q * 64 + lane;
    uint2 sv = smp[ray * 256 + j];
    float2 ar = __half22float2(__builtin_bit_cast(__half2, sv.x));
    float2 gb = __half22float2(__builtin_bit_cast(__half2, sv.y));
    float alpha = ar.x;
    float z = fmaf((float)j, dt, tmin);

    float p = 1.0f - alpha + 1e-10f;
#pragma unroll
    for (int off = 1; off < 64; off <<= 1) {
      float t = __shfl_up(p, off, 64);
      if (lane >= off) p *= t;
    }
    float tot = __shfl(p, 63, 64);
    float e = __shfl_up(p, 1, 64);
    if (lane == 0) e = 1.0f;
    float Tj = C * e;
    float w = alpha * Tj;
    racc += w * ar.y;
    gacc += w * gb.x;
    bacc += w * gb.y;
    wsum += w;
    dsum += w * z;
    C *= tot;
  }

#pragma unroll
  for (int off = 32; off > 0; off >>= 1) {
    racc += __shfl_down(racc, off, 64);
    gacc += __shfl_down(gacc, off, 64);
    bacc += __shfl_down(bacc, off, 64);
    wsum += __shfl_down(wsum, off, 64);
    dsum += __shfl_down(dsum, off, 64);
  }
  if (lane == 0) {
    float bgw = 1.0f - wsum;  // WHITE_BG
    out[ray * 3 + 0] = fminf(fmaxf(racc + bgw, 0.f), 1.f);
    out[ray * 3 + 1] = fminf(fmaxf(gacc + bgw, 0.f), 1.f);
    out[ray * 3 + 2] = fminf(fmaxf(bacc + bgw, 0.f), 1.f);
    out[NRAYS * 3 + ray] = dsum;
  }
}

// ---------------------------------------------------------------------------
// Fallback (ws too small): single-kernel fp32 render on original layout.
// ---------------------------------------------------------------------------
__device__ __forceinline__ float density_orig(const float* __restrict__ plane,
                                              const float* __restrict__ line,
                                              float cx, float cy, float cw) {
  int x0, y0, l0; float wx, wy, wl;
  grid_uv(cx, x0, wx); grid_uv(cy, y0, wy); grid_uv(cw, l0, wl);
  int base = y0 * 256 + x0;
  float s = 0.0f;
#pragma unroll 4
  for (int c = 0; c < 16; ++c) {
    const float* pc = plane + c * 65536;
    float v00 = pc[base], v01 = pc[base + 1];
    float v10 = pc[base + 256], v11 = pc[base + 257];
    float top = fmaf(wx, v01 - v00, v00);
    float bot = fmaf(wx, v11 - v10, v10);
    float mid = fmaf(wy, bot - top, top);
    float la = line[c * 256 + l0], lb = line[c * 256 + l0 + 1];
    float lv = fmaf(wl, lb - la, la);
    s += mid * lv;
  }
  return s;
}

__device__ __forceinline__ void app_orig(const float* __restrict__ plane,
                                         const float* __restrict__ line,
                                         const float* __restrict__ btR,
                                         const float* __restrict__ btG,
                                         const float* __restrict__ btB,
                                         float cx, float cy, float cw,
                                         float& dr, float& dg, float& db) {
  int x0, y0, l0; float wx, wy, wl;
  grid_uv(cx, x0, wx); grid_uv(cy, y0, wy); grid_uv(cw, l0, wl);
  int base = y0 * 256 + x0;
#pragma unroll 4
  for (int c = 0; c < 24; ++c) {
    const float* pc = plane + c * 65536;
    float v00 = pc[base], v01 = pc[base + 1];
    float v10 = pc[base + 256], v11 = pc[base + 257];
    float top = fmaf(wx, v01 - v00, v00);
    float bot = fmaf(wx, v11 - v10, v10);
    float mid = fmaf(wy, bot - top, top);
    float la = line[c * 256 + l0], lb = line[c * 256 + l0 + 1];
    float lv = fmaf(wl, lb - la, la);
    float av = mid * lv;
    dr += av * btR[c]; dg += av * btG[c]; db += av * btB[c];
  }
}

__global__ __launch_bounds__(256) void render_fallback(
    const float* __restrict__ rays, const float* __restrict__ basis,
    const float* __restrict__ aabb, const float* __restrict__ dplane,
    const float* __restrict__ dline, const float* __restrict__ aplane,
    const float* __restrict__ aline, float* __restrict__ out) {
  __shared__ float bt[3 * 72];
  int tid = threadIdx.x;
  if (tid < 216) {
    int k = tid / 72, r = tid - k * 72;
    bt[tid] = basis[r * 3 + k];
  }
  __syncthreads();
  int lane = tid & 63;
  int ray = blockIdx.x * 4 + (tid >> 6);

  float o0 = rays[ray * 6 + 0], o1 = rays[ray * 6 + 1], o2 = rays[ray * 6 + 2];
  float d0 = rays[ray * 6 + 3], d1 = rays[ray * 6 + 4], d2 = rays[ray * 6 + 5];
  float A0 = aabb[0], A1 = aabb[1], A2 = aabb[2];
  float B0 = aabb[3], B1 = aabb[4], B2 = aabb[5];
  float v0 = fabsf(d0) < 1e-6f ? 1e-6f : d0;
  float v1 = fabsf(d1) < 1e-6f ? 1e-6f : d1;
  float v2 = fabsf(d2) < 1e-6f ? 1e-6f : d2;
  float ra0 = (B0 - o0) / v0, rb0 = (A0 - o0) / v0;
  float ra1 = (B1 - o1) / v1, rb1 = (A1 - o1) / v1;
  float ra2 = (B2 - o2) / v2, rb2 = (A2 - o2) / v2;
  float tmin = fmaxf(fmaxf(fminf(ra0, rb0), fminf(ra1, rb1)), fminf(ra2, rb2));
  tmin = fmaxf(tmin, 0.05f);
  float tmax = fminf(fminf(fmaxf(ra0, rb0), fmaxf(ra1, rb1)), fmaxf(ra2, rb2));
  tmax = fmaxf(tmax, tmin + 0.001f);
  float dt = (tmax - tmin) * (1.0f / 255.0f);
  float s0 = 2.0f / (B0 - A0), s1 = 2.0f / (B1 - A1), s2 = 2.0f / (B2 - A2);

  float C = 1.0f;
  float racc = 0.f, gacc = 0.f, bacc = 0.f, wsum = 0.f, dsum = 0.f;
  for (int q = 0; q < 4; ++q) {
    int j = q * 64 + lane;
    float sfrac = (float)j * (1.0f / 255.0f);
    float z = tmin * (1.0f - sfrac) + tmax * sfrac;
    float c0 = (o0 + d0 * z - A0) * s0 - 1.0f;
    float c1 = (o1 + d1 * z - A1) * s1 - 1.0f;
    float c2 = (o2 + d2 * z - A2) * s2 - 1.0f;
    bool inside = (fabsf(c0) <= 1.0f) && (fabsf(c1) <= 1.0f) && (fabsf(c2) <= 1.0f);
    float alpha = 0.f, cr = 0.f, cg = 0.f, cb = 0.f;
    if (inside) {
      float sig = 0.f, dr = 0.f, dg = 0.f, db = 0.f;
      sig += density_orig(dplane + 0 * 1048576, dline + 0 * 4096, c0, c1, c2);
      sig += density_orig(dplane + 1 * 1048576, dline + 1 * 4096, c0, c2, c1);
      sig += density_orig(dplane + 2 * 1048576, dline + 2 * 4096, c1, c2, c0);
      app_orig(aplane + 0 * 1572864, aline + 0 * 6144,
               &bt[0 * 72 + 0], &bt[1 * 72 + 0], &bt[2 * 72 + 0],
               c0, c1, c2, dr, dg, db);
      app_orig(aplane + 1 * 1572864, aline + 1 * 6144,
               &bt[0 * 72 + 24], &bt[1 * 72 + 24], &bt[2 * 72 + 24],
               c0, c2, c1, dr, dg, db);
      app_orig(aplane + 2 * 1572864, aline + 2 * 6144,
               &bt[0 * 72 + 48], &bt[1 * 72 + 48], &bt[2 * 72 + 48],
               c1, c2, c0, dr, dg, db);
      float sp = fmaxf(sig, 0.f) + log1pf(expf(-fabsf(sig)));
      alpha = 1.0f - expf(-sp * dt);
      cr = 1.0f / (1.0f + expf(-dr));
      cg = 1.0f / (1.0f + expf(-dg));
      cb = 1.0f / (1.0f + expf(-db));
    }
    float p = 1.0f - alpha + 1e-10f;
#pragma unroll
    for (int off = 1; off < 64; off <<= 1) {
      float t = __shfl_up(p, off, 64);
      if (lane >= off) p *= t;
    }
    float tot = __shfl(p, 63, 64);
    float e = __shfl_up(p, 1, 64);
    if (lane == 0) e = 1.0f;
    float Tj = C * e;
    float w = alpha * Tj;
    racc += w * cr; gacc += w * cg; bacc += w * cb;
    wsum += w; dsum += w * z;
    C *= tot;
  }
#pragma unroll
  for (int off = 32; off > 0; off >>= 1) {
    racc += __shfl_down(racc, off, 64);
    gacc += __shfl_down(gacc, off, 64);
    bacc += __shfl_down(bacc, off, 64);
    wsum += __shfl_down(wsum, off, 64);
    dsum += __shfl_down(dsum, off, 64);
  }
  if (lane == 0) {
    float bgw = 1.0f - wsum;
    out[ray * 3 + 0] = fminf(fmaxf(racc + bgw, 0.f), 1.f);
    out[ray * 3 + 1] = fminf(fmaxf(gacc + bgw, 0.f), 1.f);
    out[ray * 3 + 2] = fminf(fmaxf(bacc + bgw, 0.f), 1.f);
    out[NRAYS * 3 + ray] = dsum;
  }
}

extern "C" void kernel_launch(void* const* d_in, const int* in_sizes, int n_in,
                              void* d_out, int out_size, void* d_ws, size_t ws_size,
                              hipStream_t stream) {
  const float* rays  = (const float*)d_in[0];
  const float* dp    = (const float*)d_in[1];
  const float* dl    = (const float*)d_in[2];
  const float* ap    = (const float*)d_in[3];
  const float* al    = (const float*)d_in[4];
  const float* basis = (const float*)d_in[5];
  const float* aabb  = (const float*)d_in[6];
  float* out = (float*)d_out;

  if (ws_size >= WS_NEED) {
    char* ws = (char*)d_ws;
    __half* dpt = (__half*)(ws + DPT_B);
    __half* dlt = (__half*)(ws + DLT_B);
    unsigned char* apt = (unsigned char*)(ws + APT_B);
    unsigned char* alt = (unsigned char*)(ws + ALT_B);
    uint2* smp = (uint2*)(ws + SMP_B);
    float4* rayd = (float4*)(ws + RAY_B);
    prep_kernel<<<1558, 256, 0, stream>>>(dp, ap, dl, al, rays, aabb,
                                          dpt, apt, dlt, alt, rayd);
    sample_kernel<<<NRAYS * 2, 256, 0, stream>>>(rayd, basis, dpt, dlt, apt, alt, smp);
    scan_kernel<<<NRAYS / 4, 256, 0, stream>>>(rayd, smp, out);
  } else {
    render_fallback<<<NRAYS / 4, 256, 0, stream>>>(
        rays, basis, aabb, dp, dl, ap, al, out);
  }
}

// Round 8
// 165.168 us; speedup vs baseline: 1.7102x; 1.0363x over previous
//
#include <hip/hip_runtime.h>
#include <hip/hip_fp16.h>
#include <cmath>

#define NRAYS 4096
#define NSAMP 256
#define NSAMPLES_TOT (NRAYS * NSAMP)

// Workspace layout (byte offsets):
//   dpt fp8  [i][y][x][16]   3*65536*16 = 3145728  (16B texels)
//   dlt fp16 [i][l][16]      3*256*32   = 24576
//   apt fp8  [i][y][x][24]   3*65536*24 = 4718592  (24B texels, no pad)
//   alt fp8  [i][l][24]      3*256*24   = 18432
//   smp [ray][samp] 2xhalf2  = 8388608
//   rayd [ray] 2xfloat4      = 131072
static constexpr size_t DPT_B = 0;
static constexpr size_t DLT_B = 3145728;
static constexpr size_t APT_B = DLT_B + 24576;     // 3170304
static constexpr size_t ALT_B = APT_B + 4718592;   // 7888896
static constexpr size_t SMP_B = ALT_B + 18432;     // 7907328
static constexpr size_t RAY_B = SMP_B + 8388608;   // 16295936
static constexpr size_t WS_NEED = RAY_B + 131072;  // 16427008 (~15.7 MiB)

typedef _Float16 __attribute__((ext_vector_type(2))) v2h;
typedef __attribute__((ext_vector_type(2))) float f32x2;

struct u96 { unsigned x, y, z; };  // 12B, align 4 -> dwordx3

__device__ __forceinline__ u96 ld12(const void* p) {
  u96 v;
  __builtin_memcpy(&v, p, 12);
  return v;
}

__device__ __forceinline__ float dot2acc(__half2 a, __half2 b, float c) {
  return __builtin_amdgcn_fdot2(__builtin_bit_cast(v2h, a),
                                __builtin_bit_cast(v2h, b), c, false);
}

__device__ __forceinline__ __half2 lerp2(__half2 a, __half2 b, __half2 w) {
  return __hfma2(w, __hsub2(b, a), a);
}

// 16B load -> 4x half2
__device__ __forceinline__ void ld8h(const __half* p, __half2 h[4]) {
  uint4 r = *(const uint4*)p;
  h[0] = __builtin_bit_cast(__half2, r.x);
  h[1] = __builtin_bit_cast(__half2, r.y);
  h[2] = __builtin_bit_cast(__half2, r.z);
  h[3] = __builtin_bit_cast(__half2, r.w);
}

__device__ __forceinline__ unsigned pack2h(float a, float b) {
  return __builtin_bit_cast(unsigned, __floats2half2_rn(a, b));
}

// dword of 4 fp8(e4m3) -> 2x half2 (HW cvt + pack)
__device__ __forceinline__ void dec4f8h(unsigned w, __half2& h0, __half2& h1) {
  f32x2 lo = __builtin_amdgcn_cvt_pk_f32_fp8((int)w, false);
  f32x2 hi = __builtin_amdgcn_cvt_pk_f32_fp8((int)w, true);
  h0 = __floats2half2_rn(lo.x, lo.y);
  h1 = __floats2half2_rn(hi.x, hi.y);
}

__device__ __forceinline__ void dec8f8(uint2 q, __half2 h[4]) {
  dec4f8h(q.x, h[0], h[1]);
  dec4f8h(q.y, h[2], h[3]);
}

__device__ __forceinline__ void dec12f8(u96 q, __half2 h[6]) {
  dec4f8h(q.x, h[0], h[1]);
  dec4f8h(q.y, h[2], h[3]);
  dec4f8h(q.z, h[4], h[5]);
}

// 4 floats -> dword of 4 fp8(e4m3)
__device__ __forceinline__ unsigned pk4f8(float a, float b, float c, float d) {
  int w = __builtin_amdgcn_cvt_pk_fp8_f32(a, b, 0, false);
  w = __builtin_amdgcn_cvt_pk_fp8_f32(c, d, w, true);
  return (unsigned)w;
}

// align_corners=True grid coord -> (i0, frac). N=256 fixed.
__device__ __forceinline__ void grid_uv(float c, int& i0, float& w) {
  float f = (c + 1.0f) * 127.5f;
  float fl = floorf(f);
  fl = fminf(fmaxf(fl, 0.0f), 254.0f);
  i0 = (int)fl;
  w = f - fl;
}

__device__ __forceinline__ void bilin_w(float wx, float wy, __half2& W00,
                                        __half2& W01, __half2& W10, __half2& W11) {
  float ix = 1.0f - wx, iy = 1.0f - wy;
  W00 = __float2half2_rn(ix * iy);
  W01 = __float2half2_rn(wx * iy);
  W10 = __float2half2_rn(ix * wy);
  W11 = __float2half2_rn(wx * wy);
}

// ---------------------------------------------------------------------------
// Prep kernel: texture transpose+quantize AND per-ray precompute.
// blocks [0,768): density planes fp8 16B; [768,1536): app planes fp8 24B;
// 1536-1538 density lines fp16; 1539-1541 app lines fp8; [1542,1558): rays.
// ---------------------------------------------------------------------------
__global__ __launch_bounds__(256) void prep_kernel(
    const float* __restrict__ dp, const float* __restrict__ ap,
    const float* __restrict__ dl, const float* __restrict__ al,
    const float* __restrict__ rays, const float* __restrict__ aabb,
    unsigned char* __restrict__ dpt, unsigned char* __restrict__ apt,
    __half* __restrict__ dlt, unsigned char* __restrict__ alt,
    float4* __restrict__ rd) {
  __shared__ float tile[24][257];
  int b = blockIdx.x, x = threadIdx.x;
  if (b < 768) {
    int i = b >> 8, y = b & 255;
    const float* src = dp + (size_t)(i * 16) * 65536 + y * 256;
#pragma unroll
    for (int c = 0; c < 16; ++c) tile[c][x] = src[c * 65536 + x];
    __syncthreads();
    float f[16];
#pragma unroll
    for (int c = 0; c < 16; ++c) f[c] = tile[c][x];
    uint4 v;
    v.x = pk4f8(f[0], f[1], f[2], f[3]);
    v.y = pk4f8(f[4], f[5], f[6], f[7]);
    v.z = pk4f8(f[8], f[9], f[10], f[11]);
    v.w = pk4f8(f[12], f[13], f[14], f[15]);
    *(uint4*)(dpt + ((size_t)(i << 16) + (y << 8) + x) * 16) = v;
  } else if (b < 1536) {
    int t = b - 768;
    int i = t >> 8, y = t & 255;
    const float* src = ap + (size_t)(i * 24) * 65536 + y * 256;
#pragma unroll
    for (int c = 0; c < 24; ++c) tile[c][x] = src[c * 65536 + x];
    __syncthreads();
    float f[24];
#pragma unroll
    for (int c = 0; c < 24; ++c) f[c] = tile[c][x];
    unsigned* dst = (unsigned*)(apt + ((size_t)(i << 16) + (y << 8) + x) * 24);
#pragma unroll
    for (int k = 0; k < 6; ++k)
      dst[k] = pk4f8(f[k * 4], f[k * 4 + 1], f[k * 4 + 2], f[k * 4 + 3]);
  } else if (b < 1539) {
    int i = b - 1536, l = x;
    float f[16];
#pragma unroll
    for (int c = 0; c < 16; ++c) f[c] = dl[(i * 16 + c) * 256 + l];
    uint4 v0, v1;
    v0.x = pack2h(f[0], f[1]);   v0.y = pack2h(f[2], f[3]);
    v0.z = pack2h(f[4], f[5]);   v0.w = pack2h(f[6], f[7]);
    v1.x = pack2h(f[8], f[9]);   v1.y = pack2h(f[10], f[11]);
    v1.z = pack2h(f[12], f[13]); v1.w = pack2h(f[14], f[15]);
    uint4* dst = (uint4*)(dlt + (i * 256 + l) * 16);
    dst[0] = v0; dst[1] = v1;
  } else if (b < 1542) {
    int i = b - 1539, l = x;
    float f[24];
#pragma unroll
    for (int c = 0; c < 24; ++c) f[c] = al[(i * 24 + c) * 256 + l];
    unsigned* dst = (unsigned*)(alt + (i * 256 + l) * 24);
#pragma unroll
    for (int k = 0; k < 6; ++k)
      dst[k] = pk4f8(f[k * 4], f[k * 4 + 1], f[k * 4 + 2], f[k * 4 + 3]);
  } else {
    int r = (b - 1542) * 256 + x;
    if (r < NRAYS) {
      float o0 = rays[r * 6 + 0], o1 = rays[r * 6 + 1], o2 = rays[r * 6 + 2];
      float d0 = rays[r * 6 + 3], d1 = rays[r * 6 + 4], d2 = rays[r * 6 + 5];
      float A0 = aabb[0], A1 = aabb[1], A2 = aabb[2];
      float B0 = aabb[3], B1 = aabb[4], B2 = aabb[5];
      float v0 = fabsf(d0) < 1e-6f ? 1e-6f : d0;
      float v1 = fabsf(d1) < 1e-6f ? 1e-6f : d1;
      float v2 = fabsf(d2) < 1e-6f ? 1e-6f : d2;
      float ra0 = (B0 - o0) / v0, rb0 = (A0 - o0) / v0;
      float ra1 = (B1 - o1) / v1, rb1 = (A1 - o1) / v1;
      float ra2 = (B2 - o2) / v2, rb2 = (A2 - o2) / v2;
      float tmin = fmaxf(fmaxf(fminf(ra0, rb0), fminf(ra1, rb1)), fminf(ra2, rb2));
      tmin = fmaxf(tmin, 0.05f);
      float tmax = fminf(fminf(fmaxf(ra0, rb0), fmaxf(ra1, rb1)), fmaxf(ra2, rb2));
      tmax = fmaxf(tmax, tmin + 0.001f);
      float dt = (tmax - tmin) * (1.0f / 255.0f);
      float s0 = 2.0f / (B0 - A0), s1 = 2.0f / (B1 - A1), s2 = 2.0f / (B2 - A2);
      float4 a2, b2;
      a2.x = (o0 - A0) * s0 - 1.0f; a2.y = (o1 - A1) * s1 - 1.0f;
      a2.z = (o2 - A2) * s2 - 1.0f; a2.w = tmin;
      b2.x = d0 * s0; b2.y = d1 * s1; b2.z = d2 * s2; b2.w = dt;
      rd[r * 2] = a2;
      rd[r * 2 + 1] = b2;
    }
  }
}

// ---------------------------------------------------------------------------
// density mode (fp8 plane, fp16 line): lane sub owns 8 channels. 8B loads.
// ---------------------------------------------------------------------------
__device__ __forceinline__ float density_f8(const unsigned char* __restrict__ pl,
                                            const __half* __restrict__ ln,
                                            int x0, int y0, int l0,
                                            __half2 W00, __half2 W01,
                                            __half2 W10, __half2 W11,
                                            __half2 wl, int sub, float acc) {
  const unsigned char* p = pl + (size_t)((y0 * 256 + x0) << 4) + sub * 8;
  uint2 q00 = *(const uint2*)p;
  uint2 q01 = *(const uint2*)(p + 16);
  uint2 q10 = *(const uint2*)(p + 4096);
  uint2 q11 = *(const uint2*)(p + 4096 + 16);
  __half2 A[4], B[4], C[4], D[4], la[4], lb[4];
  dec8f8(q00, A); dec8f8(q01, B); dec8f8(q10, C); dec8f8(q11, D);
  const __half* lp = ln + (l0 << 4) + sub * 8;
  ld8h(lp, la); ld8h(lp + 16, lb);
#pragma unroll
  for (int r = 0; r < 4; ++r) {
    __half2 m = __hmul2(W00, A[r]);
    m = __hfma2(W01, B[r], m);
    m = __hfma2(W10, C[r], m);
    m = __hfma2(W11, D[r], m);
    __half2 l = lerp2(la[r], lb[r], wl);
    acc = dot2acc(m, l, acc);
  }
  return acc;
}

// ---------------------------------------------------------------------------
// app mode (fp8, 24B texels): lane sub owns 12 channels. 12B loads.
// ---------------------------------------------------------------------------
__device__ __forceinline__ void app_f8(const unsigned char* __restrict__ pl,
                                       const unsigned char* __restrict__ ln,
                                       const __half2* __restrict__ btR,
                                       const __half2* __restrict__ btG,
                                       const __half2* __restrict__ btB,
                                       int x0, int y0, int l0,
                                       __half2 W00, __half2 W01,
                                       __half2 W10, __half2 W11,
                                       __half2 wl, int sub,
                                       float& dr, float& dg, float& db) {
  const unsigned char* p = pl + (size_t)(y0 * 256 + x0) * 24 + sub * 12;
  u96 qA = ld12(p);
  u96 qB = ld12(p + 24);
  u96 qC = ld12(p + 6144);
  u96 qD = ld12(p + 6144 + 24);
  const unsigned char* lp = ln + l0 * 24 + sub * 12;
  u96 qLA = ld12(lp);
  u96 qLB = ld12(lp + 24);
  __half2 A[6], B[6], C[6], D[6], LA[6], LB[6];
  dec12f8(qA, A); dec12f8(qB, B); dec12f8(qC, C); dec12f8(qD, D);
  dec12f8(qLA, LA); dec12f8(qLB, LB);
#pragma unroll
  for (int r = 0; r < 6; ++r) {
    __half2 m = __hmul2(W00, A[r]);
    m = __hfma2(W01, B[r], m);
    m = __hfma2(W10, C[r], m);
    m = __hfma2(W11, D[r], m);
    __half2 l = lerp2(LA[r], LB[r], wl);
    __half2 av = __hmul2(m, l);
    dr = dot2acc(av, btR[r], dr);
    dg = dot2acc(av, btG[r], dg);
    db = dot2acc(av, btB[r], db);
  }
}

// ---------------------------------------------------------------------------
// Sample kernel: 2 lanes per sample; block = 128 samples of one ray.
// 8192 blocks x 256 threads.
// ---------------------------------------------------------------------------
__global__ __launch_bounds__(256) void sample_kernel(
    const float4* __restrict__ rd, const float* __restrict__ basis,
    const unsigned char* __restrict__ dpt, const __half* __restrict__ dlt,
    const unsigned char* __restrict__ apt, const unsigned char* __restrict__ alt,
    uint2* __restrict__ smp) {
  __shared__ __align__(16) __half bth[3][3][24];  // [k][mode][ch]
  int tid = threadIdx.x;
  if (tid < 216) {  // 216 <= 256: single pass covers all entries
    int k = tid / 72, rem = tid - k * 72;
    int m = rem / 24, c = rem - m * 24;
    bth[k][m][c] = __float2half(basis[(m * 24 + c) * 3 + k]);
  }
  __syncthreads();

  int ray = blockIdx.x >> 1;
  int j = ((blockIdx.x & 1) << 7) + (tid >> 1);
  int sub = tid & 1;

  float4 ra = rd[ray * 2];
  float4 rb = rd[ray * 2 + 1];
  float z = fmaf((float)j, rb.w, ra.w);
  float c0 = fmaf(rb.x, z, ra.x);
  float c1 = fmaf(rb.y, z, ra.y);
  float c2 = fmaf(rb.z, z, ra.z);
  bool inside = (fabsf(c0) <= 1.0f) && (fabsf(c1) <= 1.0f) && (fabsf(c2) <= 1.0f);

  float sig = 0.f, dr = 0.f, dg = 0.f, db = 0.f;
  if (inside) {
    int i0, i1, i2;
    float w0, w1, w2;
    grid_uv(c0, i0, w0);
    grid_uv(c1, i1, w1);
    grid_uv(c2, i2, w2);
    __half2 h0 = __float2half2_rn(w0);
    __half2 h1 = __float2half2_rn(w1);
    __half2 h2 = __float2half2_rn(w2);
    // MAT_MODE = [(0,1),(0,2),(1,2)], VEC_MODE = [2,1,0]
    __half2 Wa00, Wa01, Wa10, Wa11;  // mode 0: (w0,w1)
    __half2 Wb00, Wb01, Wb10, Wb11;  // mode 1: (w0,w2)
    __half2 Wc00, Wc01, Wc10, Wc11;  // mode 2: (w1,w2)
    bilin_w(w0, w1, Wa00, Wa01, Wa10, Wa11);
    bilin_w(w0, w2, Wb00, Wb01, Wb10, Wb11);
    bilin_w(w1, w2, Wc00, Wc01, Wc10, Wc11);

    sig = density_f8(dpt + 0 * 1048576, dlt + 0 * 4096, i0, i1, i2,
                     Wa00, Wa01, Wa10, Wa11, h2, sub, sig);
    sig = density_f8(dpt + 1 * 1048576, dlt + 1 * 4096, i0, i2, i1,
                     Wb00, Wb01, Wb10, Wb11, h1, sub, sig);
    sig = density_f8(dpt + 2 * 1048576, dlt + 2 * 4096, i1, i2, i0,
                     Wc00, Wc01, Wc10, Wc11, h0, sub, sig);
    app_f8(apt + 0 * 1572864, alt + 0 * 6144,
           (const __half2*)&bth[0][0][sub * 12], (const __half2*)&bth[1][0][sub * 12],
           (const __half2*)&bth[2][0][sub * 12], i0, i1, i2,
           Wa00, Wa01, Wa10, Wa11, h2, sub, dr, dg, db);
    app_f8(apt + 1 * 1572864, alt + 1 * 6144,
           (const __half2*)&bth[0][1][sub * 12], (const __half2*)&bth[1][1][sub * 12],
           (const __half2*)&bth[2][1][sub * 12], i0, i2, i1,
           Wb00, Wb01, Wb10, Wb11, h1, sub, dr, dg, db);
    app_f8(apt + 2 * 1572864, alt + 2 * 6144,
           (const __half2*)&bth[0][2][sub * 12], (const __half2*)&bth[1][2][sub * 12],
           (const __half2*)&bth[2][2][sub * 12], i1, i2, i0,
           Wc00, Wc01, Wc10, Wc11, h0, sub, dr, dg, db);
  }
  // reduce over the 2-lane group
  sig += __shfl_xor(sig, 1, 64);
  dr += __shfl_xor(dr, 1, 64);
  dg += __shfl_xor(dg, 1, 64);
  db += __shfl_xor(db, 1, 64);

  if (sub == 0) {
    float sp = fmaxf(sig, 0.f) + log1pf(expf(-fabsf(sig)));  // softplus
    float alpha = inside ? (1.0f - expf(-sp * rb.w)) : 0.0f;
    float cr = 1.0f / (1.0f + expf(-dr));
    float cg = 1.0f / (1.0f + expf(-dg));
    float cb = 1.0f / (1.0f + expf(-db));
    uint2 sv;
    sv.x = pack2h(alpha, cr);
    sv.y = pack2h(cg, cb);
    smp[ray * 256 + j] = sv;
  }
}

// ---------------------------------------------------------------------------
// Scan kernel: per-ray transmittance scan + composite. One wave per ray.
// ---------------------------------------------------------------------------
__global__ __launch_bounds__(256) void scan_kernel(
    const float4* __restrict__ rd, const uint2* __restrict__ smp,
    float* __restrict__ out) {
  int tid = threadIdx.x;
  int lane = tid & 63;
  int ray = blockIdx.x * 4 + (tid >> 6);

  float tmin = rd[ray * 2].w;
  float dt = rd[ray * 2 + 1].w;

  float C = 1.0f;
  float racc = 0.f, gacc = 0.f, bacc = 0.f, wsum = 0.f, dsum = 0.f;

  for (int q = 0; q < 4; ++q) {
    int j = q * 64 + lane;
    uint2 sv = smp[ray * 256 + j];
    float2 ar = __half22float2(__builtin_bit_cast(__half2, sv.x));
    float2 gb = __half22float2(__builtin_bit_cast(__half2, sv.y));
    float alpha = ar.x;
    float z = fmaf((float)j, dt, tmin);

    float p = 1.0f - alpha + 1e-10f;
#pragma unroll
    for (int off = 1; off < 64; off <<= 1) {
      float t = __shfl_up(p, off, 64);
      if (lane >= off) p *= t;
    }
    float tot = __shfl(p, 63, 64);
    float e = __shfl_up(p, 1, 64);
    if (lane == 0) e = 1.0f;
    float Tj = C * e;
    float w = alpha * Tj;
    racc += w * ar.y;
    gacc += w * gb.x;
    bacc += w * gb.y;
    wsum += w;
    dsum += w * z;
    C *= tot;
  }

#pragma unroll
  for (int off = 32; off > 0; off >>= 1) {
    racc += __shfl_down(racc, off, 64);
    gacc += __shfl_down(gacc, off, 64);
    bacc += __shfl_down(bacc, off, 64);
    wsum += __shfl_down(wsum, off, 64);
    dsum += __shfl_down(dsum, off, 64);
  }
  if (lane == 0) {
    float bgw = 1.0f - wsum;  // WHITE_BG
    out[ray * 3 + 0] = fminf(fmaxf(racc + bgw, 0.f), 1.f);
    out[ray * 3 + 1] = fminf(fmaxf(gacc + bgw, 0.f), 1.f);
    out[ray * 3 + 2] = fminf(fmaxf(bacc + bgw, 0.f), 1.f);
    out[NRAYS * 3 + ray] = dsum;
  }
}

// ---------------------------------------------------------------------------
// Fallback (ws too small): single-kernel fp32 render on original layout.
// ---------------------------------------------------------------------------
__device__ __forceinline__ float density_orig(const float* __restrict__ plane,
                                              const float* __restrict__ line,
                                              float cx, float cy, float cw) {
  int x0, y0, l0; float wx, wy, wl;
  grid_uv(cx, x0, wx); grid_uv(cy, y0, wy); grid_uv(cw, l0, wl);
  int base = y0 * 256 + x0;
  float s = 0.0f;
#pragma unroll 4
  for (int c = 0; c < 16; ++c) {
    const float* pc = plane + c * 65536;
    float v00 = pc[base], v01 = pc[base + 1];
    float v10 = pc[base + 256], v11 = pc[base + 257];
    float top = fmaf(wx, v01 - v00, v00);
    float bot = fmaf(wx, v11 - v10, v10);
    float mid = fmaf(wy, bot - top, top);
    float la = line[c * 256 + l0], lb = line[c * 256 + l0 + 1];
    float lv = fmaf(wl, lb - la, la);
    s += mid * lv;
  }
  return s;
}

__device__ __forceinline__ void app_orig(const float* __restrict__ plane,
                                         const float* __restrict__ line,
                                         const float* __restrict__ btR,
                                         const float* __restrict__ btG,
                                         const float* __restrict__ btB,
                                         float cx, float cy, float cw,
                                         float& dr, float& dg, float& db) {
  int x0, y0, l0; float wx, wy, wl;
  grid_uv(cx, x0, wx); grid_uv(cy, y0, wy); grid_uv(cw, l0, wl);
  int base = y0 * 256 + x0;
#pragma unroll 4
  for (int c = 0; c < 24; ++c) {
    const float* pc = plane + c * 65536;
    float v00 = pc[base], v01 = pc[base + 1];
    float v10 = pc[base + 256], v11 = pc[base + 257];
    float top = fmaf(wx, v01 - v00, v00);
    float bot = fmaf(wx, v11 - v10, v10);
    float mid = fmaf(wy, bot - top, top);
    float la = line[c * 256 + l0], lb = line[c * 256 + l0 + 1];
    float lv = fmaf(wl, lb - la, la);
    float av = mid * lv;
    dr += av * btR[c]; dg += av * btG[c]; db += av * btB[c];
  }
}

__global__ __launch_bounds__(256) void render_fallback(
    const float* __restrict__ rays, const float* __restrict__ basis,
    const float* __restrict__ aabb, const float* __restrict__ dplane,
    const float* __restrict__ dline, const float* __restrict__ aplane,
    const float* __restrict__ aline, float* __restrict__ out) {
  __shared__ float bt[3 * 72];
  int tid = threadIdx.x;
  if (tid < 216) {
    int k = tid / 72, r = tid - k * 72;
    bt[tid] = basis[r * 3 + k];
  }
  __syncthreads();
  int lane = tid & 63;
  int ray = blockIdx.x * 4 + (tid >> 6);

  float o0 = rays[ray * 6 + 0], o1 = rays[ray * 6 + 1], o2 = rays[ray * 6 + 2];
  float d0 = rays[ray * 6 + 3], d1 = rays[ray * 6 + 4], d2 = rays[ray * 6 + 5];
  float A0 = aabb[0], A1 = aabb[1], A2 = aabb[2];
  float B0 = aabb[3], B1 = aabb[4], B2 = aabb[5];
  float v0 = fabsf(d0) < 1e-6f ? 1e-6f : d0;
  float v1 = fabsf(d1) < 1e-6f ? 1e-6f : d1;
  float v2 = fabsf(d2) < 1e-6f ? 1e-6f : d2;
  float ra0 = (B0 - o0) / v0, rb0 = (A0 - o0) / v0;
  float ra1 = (B1 - o1) / v1, rb1 = (A1 - o1) / v1;
  float ra2 = (B2 - o2) / v2, rb2 = (A2 - o2) / v2;
  float tmin = fmaxf(fmaxf(fminf(ra0, rb0), fminf(ra1, rb1)), fminf(ra2, rb2));
  tmin = fmaxf(tmin, 0.05f);
  float tmax = fminf(fminf(fmaxf(ra0, rb0), fmaxf(ra1, rb1)), fmaxf(ra2, rb2));
  tmax = fmaxf(tmax, tmin + 0.001f);
  float dt = (tmax - tmin) * (1.0f / 255.0f);
  float s0 = 2.0f / (B0 - A0), s1 = 2.0f / (B1 - A1), s2 = 2.0f / (B2 - A2);

  float C = 1.0f;
  float racc = 0.f, gacc = 0.f, bacc = 0.f, wsum = 0.f, dsum = 0.f;
  for (int q = 0; q < 4; ++q) {
    int j = q * 64 + lane;
    float sfrac = (float)j * (1.0f / 255.0f);
    float z = tmin * (1.0f - sfrac) + tmax * sfrac;
    float c0 = (o0 + d0 * z - A0) * s0 - 1.0f;
    float c1 = (o1 + d1 * z - A1) * s1 - 1.0f;
    float c2 = (o2 + d2 * z - A2) * s2 - 1.0f;
    bool inside = (fabsf(c0) <= 1.0f) && (fabsf(c1) <= 1.0f) && (fabsf(c2) <= 1.0f);
    float alpha = 0.f, cr = 0.f, cg = 0.f, cb = 0.f;
    if (inside) {
      float sig = 0.f, dr = 0.f, dg = 0.f, db = 0.f;
      sig += density_orig(dplane + 0 * 1048576, dline + 0 * 4096, c0, c1, c2);
      sig += density_orig(dplane + 1 * 1048576, dline + 1 * 4096, c0, c2, c1);
      sig += density_orig(dplane + 2 * 1048576, dline + 2 * 4096, c1, c2, c0);
      app_orig(aplane + 0 * 1572864, aline + 0 * 6144,
               &bt[0 * 72 + 0], &bt[1 * 72 + 0], &bt[2 * 72 + 0],
               c0, c1, c2, dr, dg, db);
      app_orig(aplane + 1 * 1572864, aline + 1 * 6144,
               &bt[0 * 72 + 24], &bt[1 * 72 + 24], &bt[2 * 72 + 24],
               c0, c2, c1, dr, dg, db);
      app_orig(aplane + 2 * 1572864, aline + 2 * 6144,
               &bt[0 * 72 + 48], &bt[1 * 72 + 48], &bt[2 * 72 + 48],
               c1, c2, c0, dr, dg, db);
      float sp = fmaxf(sig, 0.f) + log1pf(expf(-fabsf(sig)));
      alpha = 1.0f - expf(-sp * dt);
      cr = 1.0f / (1.0f + expf(-dr));
      cg = 1.0f / (1.0f + expf(-dg));
      cb = 1.0f / (1.0f + expf(-db));
    }
    float p = 1.0f - alpha + 1e-10f;
#pragma unroll
    for (int off = 1; off < 64; off <<= 1) {
      float t = __shfl_up(p, off, 64);
      if (lane >= off) p *= t;
    }
    float tot = __shfl(p, 63, 64);
    float e = __shfl_up(p, 1, 64);
    if (lane == 0) e = 1.0f;
    float Tj = C * e;
    float w = alpha * Tj;
    racc += w * cr; gacc += w * cg; bacc += w * cb;
    wsum += w; dsum += w * z;
    C *= tot;
  }
#pragma unroll
  for (int off = 32; off > 0; off >>= 1) {
    racc += __shfl_down(racc, off, 64);
    gacc += __shfl_down(gacc, off, 64);
    bacc += __shfl_down(bacc, off, 64);
    wsum += __shfl_down(wsum, off, 64);
    dsum += __shfl_down(dsum, off, 64);
  }
  if (lane == 0) {
    float bgw = 1.0f - wsum;
    out[ray * 3 + 0] = fminf(fmaxf(racc + bgw, 0.f), 1.f);
    out[ray * 3 + 1] = fminf(fmaxf(gacc + bgw, 0.f), 1.f);
    out[ray * 3 + 2] = fminf(fmaxf(bacc + bgw, 0.f), 1.f);
    out[NRAYS * 3 + ray] = dsum;
  }
}

extern "C" void kernel_launch(void* const* d_in, const int* in_sizes, int n_in,
                              void* d_out, int out_size, void* d_ws, size_t ws_size,
                              hipStream_t stream) {
  const float* rays  = (const float*)d_in[0];
  const float* dp    = (const float*)d_in[1];
  const float* dl    = (const float*)d_in[2];
  const float* ap    = (const float*)d_in[3];
  const float* al    = (const float*)d_in[4];
  const float* basis = (const float*)d_in[5];
  const float* aabb  = (const float*)d_in[6];
  float* out = (float*)d_out;

  if (ws_size >= WS_NEED) {
    char* ws = (char*)d_ws;
    unsigned char* dpt = (unsigned char*)(ws + DPT_B);
    __half* dlt = (__half*)(ws + DLT_B);
    unsigned char* apt = (unsigned char*)(ws + APT_B);
    unsigned char* alt = (unsigned char*)(ws + ALT_B);
    uint2* smp = (uint2*)(ws + SMP_B);
    float4* rayd = (float4*)(ws + RAY_B);
    prep_kernel<<<1558, 256, 0, stream>>>(dp, ap, dl, al, rays, aabb,
                                          dpt, apt, dlt, alt, rayd);
    sample_kernel<<<NRAYS * 2, 256, 0, stream>>>(rayd, basis, dpt, dlt, apt, alt, smp);
    scan_kernel<<<NRAYS / 4, 256, 0, stream>>>(rayd, smp, out);
  } else {
    render_fallback<<<NRAYS / 4, 256, 0, stream>>>(
        rays, basis, aabb, dp, dl, ap, al, out);
  }
}

// Round 9
// 153.676 us; speedup vs baseline: 1.8381x; 1.0748x over previous
//
#include <hip/hip_runtime.h>
#include <hip/hip_fp16.h>
#include <cmath>

#define NRAYS 4096
#define NSAMP 256
#define NSAMPLES_TOT (NRAYS * NSAMP)

// Workspace layout (byte offsets):
//   dpt fp8  [i][y][x][16]   3*65536*16 = 3145728  (16B texels)
//   dlt fp16 [i][l][16]      3*256*32   = 24576
//   apt fp8  [i][y][x][32]   3*65536*32 = 6291456  (32B texels, ch24..31 pad)
//   alt fp8  [i][l][32]      3*256*32   = 24576
//   smp [ray][samp] 2xhalf2  = 8388608
//   rayd [ray] 2xfloat4      = 131072
static constexpr size_t DPT_B = 0;
static constexpr size_t DLT_B = 3145728;
static constexpr size_t APT_B = DLT_B + 24576;     // 3170304
static constexpr size_t ALT_B = APT_B + 6291456;   // 9461760
static constexpr size_t SMP_B = ALT_B + 24576;     // 9486336
static constexpr size_t RAY_B = SMP_B + 8388608;   // 17874944
static constexpr size_t WS_NEED = RAY_B + 131072;  // 18006016 (~17.2 MiB)

typedef _Float16 __attribute__((ext_vector_type(2))) v2h;
typedef __attribute__((ext_vector_type(2))) float f32x2;

#if defined(__has_builtin)
#if __has_builtin(__builtin_amdgcn_cvt_scalef32_pk_f16_fp8)
#define HAS_SCVT 1
#endif
#endif
#ifndef HAS_SCVT
#define HAS_SCVT 0
#endif

__device__ __forceinline__ float dot2acc(__half2 a, __half2 b, float c) {
  return __builtin_amdgcn_fdot2(__builtin_bit_cast(v2h, a),
                                __builtin_bit_cast(v2h, b), c, false);
}

__device__ __forceinline__ __half2 lerp2(__half2 a, __half2 b, __half2 w) {
  return __hfma2(w, __hsub2(b, a), a);
}

// 16B load -> 4x half2
__device__ __forceinline__ void ld8h(const __half* p, __half2 h[4]) {
  uint4 r = *(const uint4*)p;
  h[0] = __builtin_bit_cast(__half2, r.x);
  h[1] = __builtin_bit_cast(__half2, r.y);
  h[2] = __builtin_bit_cast(__half2, r.z);
  h[3] = __builtin_bit_cast(__half2, r.w);
}

__device__ __forceinline__ unsigned pack2h(float a, float b) {
  return __builtin_bit_cast(unsigned, __floats2half2_rn(a, b));
}

// dword of 4 fp8(e4m3) -> 2x half2. gfx950 direct fp8->f16 (1 inst per half2)
// when available; else HW fp8->f32 cvt + pack.
__device__ __forceinline__ void dec4f8h(unsigned w, __half2& h0, __half2& h1) {
#if HAS_SCVT
  v2h a = __builtin_amdgcn_cvt_scalef32_pk_f16_fp8((int)w, 1.0f, false);
  v2h b = __builtin_amdgcn_cvt_scalef32_pk_f16_fp8((int)w, 1.0f, true);
  h0 = __builtin_bit_cast(__half2, a);
  h1 = __builtin_bit_cast(__half2, b);
#else
  f32x2 lo = __builtin_amdgcn_cvt_pk_f32_fp8((int)w, false);
  f32x2 hi = __builtin_amdgcn_cvt_pk_f32_fp8((int)w, true);
  h0 = __floats2half2_rn(lo.x, lo.y);
  h1 = __floats2half2_rn(hi.x, hi.y);
#endif
}

__device__ __forceinline__ void dec8f8(uint2 q, __half2 h[4]) {
  dec4f8h(q.x, h[0], h[1]);
  dec4f8h(q.y, h[2], h[3]);
}

__device__ __forceinline__ void dec16f8(uint4 q, __half2 h[8]) {
  dec4f8h(q.x, h[0], h[1]);
  dec4f8h(q.y, h[2], h[3]);
  dec4f8h(q.z, h[4], h[5]);
  dec4f8h(q.w, h[6], h[7]);
}

// 4 floats -> dword of 4 fp8(e4m3)
__device__ __forceinline__ unsigned pk4f8(float a, float b, float c, float d) {
  int w = __builtin_amdgcn_cvt_pk_fp8_f32(a, b, 0, false);
  w = __builtin_amdgcn_cvt_pk_fp8_f32(c, d, w, true);
  return (unsigned)w;
}

// align_corners=True grid coord -> (i0, frac). N=256 fixed.
__device__ __forceinline__ void grid_uv(float c, int& i0, float& w) {
  float f = (c + 1.0f) * 127.5f;
  float fl = floorf(f);
  fl = fminf(fmaxf(fl, 0.0f), 254.0f);
  i0 = (int)fl;
  w = f - fl;
}

__device__ __forceinline__ void bilin_w(float wx, float wy, __half2& W00,
                                        __half2& W01, __half2& W10, __half2& W11) {
  float ix = 1.0f - wx, iy = 1.0f - wy;
  W00 = __float2half2_rn(ix * iy);
  W01 = __float2half2_rn(wx * iy);
  W10 = __float2half2_rn(ix * wy);
  W11 = __float2half2_rn(wx * wy);
}

// ---------------------------------------------------------------------------
// Prep kernel: texture transpose+quantize AND per-ray precompute.
// blocks [0,768): density planes fp8 16B; [768,1536): app planes fp8 32B;
// 1536-1538 density lines fp16; 1539-1541 app lines fp8; [1542,1558): rays.
// ---------------------------------------------------------------------------
__global__ __launch_bounds__(256) void prep_kernel(
    const float* __restrict__ dp, const float* __restrict__ ap,
    const float* __restrict__ dl, const float* __restrict__ al,
    const float* __restrict__ rays, const float* __restrict__ aabb,
    unsigned char* __restrict__ dpt, unsigned char* __restrict__ apt,
    __half* __restrict__ dlt, unsigned char* __restrict__ alt,
    float4* __restrict__ rd) {
  __shared__ float tile[24][257];
  int b = blockIdx.x, x = threadIdx.x;
  if (b < 768) {
    int i = b >> 8, y = b & 255;
    const float* src = dp + (size_t)(i * 16) * 65536 + y * 256;
#pragma unroll
    for (int c = 0; c < 16; ++c) tile[c][x] = src[c * 65536 + x];
    __syncthreads();
    float f[16];
#pragma unroll
    for (int c = 0; c < 16; ++c) f[c] = tile[c][x];
    uint4 v;
    v.x = pk4f8(f[0], f[1], f[2], f[3]);
    v.y = pk4f8(f[4], f[5], f[6], f[7]);
    v.z = pk4f8(f[8], f[9], f[10], f[11]);
    v.w = pk4f8(f[12], f[13], f[14], f[15]);
    *(uint4*)(dpt + ((size_t)(i << 16) + (y << 8) + x) * 16) = v;
  } else if (b < 1536) {
    int t = b - 768;
    int i = t >> 8, y = t & 255;
    const float* src = ap + (size_t)(i * 24) * 65536 + y * 256;
#pragma unroll
    for (int c = 0; c < 24; ++c) tile[c][x] = src[c * 65536 + x];
    __syncthreads();
    float f[24];
#pragma unroll
    for (int c = 0; c < 24; ++c) f[c] = tile[c][x];
    uint4 v0, v1;
    v0.x = pk4f8(f[0], f[1], f[2], f[3]);
    v0.y = pk4f8(f[4], f[5], f[6], f[7]);
    v0.z = pk4f8(f[8], f[9], f[10], f[11]);
    v0.w = pk4f8(f[12], f[13], f[14], f[15]);
    v1.x = pk4f8(f[16], f[17], f[18], f[19]);
    v1.y = pk4f8(f[20], f[21], f[22], f[23]);
    v1.z = 0u; v1.w = 0u;
    uint4* dst = (uint4*)(apt + ((size_t)(i << 16) + (y << 8) + x) * 32);
    dst[0] = v0; dst[1] = v1;
  } else if (b < 1539) {
    int i = b - 1536, l = x;
    float f[16];
#pragma unroll
    for (int c = 0; c < 16; ++c) f[c] = dl[(i * 16 + c) * 256 + l];
    uint4 v0, v1;
    v0.x = pack2h(f[0], f[1]);   v0.y = pack2h(f[2], f[3]);
    v0.z = pack2h(f[4], f[5]);   v0.w = pack2h(f[6], f[7]);
    v1.x = pack2h(f[8], f[9]);   v1.y = pack2h(f[10], f[11]);
    v1.z = pack2h(f[12], f[13]); v1.w = pack2h(f[14], f[15]);
    uint4* dst = (uint4*)(dlt + (i * 256 + l) * 16);
    dst[0] = v0; dst[1] = v1;
  } else if (b < 1542) {
    int i = b - 1539, l = x;
    float f[24];
#pragma unroll
    for (int c = 0; c < 24; ++c) f[c] = al[(i * 24 + c) * 256 + l];
    uint4 v0, v1;
    v0.x = pk4f8(f[0], f[1], f[2], f[3]);
    v0.y = pk4f8(f[4], f[5], f[6], f[7]);
    v0.z = pk4f8(f[8], f[9], f[10], f[11]);
    v0.w = pk4f8(f[12], f[13], f[14], f[15]);
    v1.x = pk4f8(f[16], f[17], f[18], f[19]);
    v1.y = pk4f8(f[20], f[21], f[22], f[23]);
    v1.z = 0u; v1.w = 0u;
    uint4* dst = (uint4*)(alt + (i * 256 + l) * 32);
    dst[0] = v0; dst[1] = v1;
  } else {
    int r = (b - 1542) * 256 + x;
    if (r < NRAYS) {
      float o0 = rays[r * 6 + 0], o1 = rays[r * 6 + 1], o2 = rays[r * 6 + 2];
      float d0 = rays[r * 6 + 3], d1 = rays[r * 6 + 4], d2 = rays[r * 6 + 5];
      float A0 = aabb[0], A1 = aabb[1], A2 = aabb[2];
      float B0 = aabb[3], B1 = aabb[4], B2 = aabb[5];
      float v0 = fabsf(d0) < 1e-6f ? 1e-6f : d0;
      float v1 = fabsf(d1) < 1e-6f ? 1e-6f : d1;
      float v2 = fabsf(d2) < 1e-6f ? 1e-6f : d2;
      float ra0 = (B0 - o0) / v0, rb0 = (A0 - o0) / v0;
      float ra1 = (B1 - o1) / v1, rb1 = (A1 - o1) / v1;
      float ra2 = (B2 - o2) / v2, rb2 = (A2 - o2) / v2;
      float tmin = fmaxf(fmaxf(fminf(ra0, rb0), fminf(ra1, rb1)), fminf(ra2, rb2));
      tmin = fmaxf(tmin, 0.05f);
      float tmax = fminf(fminf(fmaxf(ra0, rb0), fmaxf(ra1, rb1)), fmaxf(ra2, rb2));
      tmax = fmaxf(tmax, tmin + 0.001f);
      float dt = (tmax - tmin) * (1.0f / 255.0f);
      float s0 = 2.0f / (B0 - A0), s1 = 2.0f / (B1 - A1), s2 = 2.0f / (B2 - A2);
      float4 a2, b2;
      a2.x = (o0 - A0) * s0 - 1.0f; a2.y = (o1 - A1) * s1 - 1.0f;
      a2.z = (o2 - A2) * s2 - 1.0f; a2.w = tmin;
      b2.x = d0 * s0; b2.y = d1 * s1; b2.z = d2 * s2; b2.w = dt;
      rd[r * 2] = a2;
      rd[r * 2 + 1] = b2;
    }
  }
}

// ---------------------------------------------------------------------------
// density mode (fp8 plane, fp16 line): lane sub owns 8 channels. 8B loads.
// ---------------------------------------------------------------------------
__device__ __forceinline__ float density_f8(const unsigned char* __restrict__ pl,
                                            const __half* __restrict__ ln,
                                            int x0, int y0, int l0,
                                            __half2 W00, __half2 W01,
                                            __half2 W10, __half2 W11,
                                            __half2 wl, int sub, float acc) {
  const unsigned char* p = pl + (size_t)((y0 * 256 + x0) << 4) + sub * 8;
  uint2 q00 = *(const uint2*)p;
  uint2 q01 = *(const uint2*)(p + 16);
  uint2 q10 = *(const uint2*)(p + 4096);
  uint2 q11 = *(const uint2*)(p + 4096 + 16);
  __half2 A[4], B[4], C[4], D[4], la[4], lb[4];
  dec8f8(q00, A); dec8f8(q01, B); dec8f8(q10, C); dec8f8(q11, D);
  const __half* lp = ln + (l0 << 4) + sub * 8;
  ld8h(lp, la); ld8h(lp + 16, lb);
#pragma unroll
  for (int r = 0; r < 4; ++r) {
    __half2 m = __hmul2(W00, A[r]);
    m = __hfma2(W01, B[r], m);
    m = __hfma2(W10, C[r], m);
    m = __hfma2(W11, D[r], m);
    __half2 l = lerp2(la[r], lb[r], wl);
    acc = dot2acc(m, l, acc);
  }
  return acc;
}

// ---------------------------------------------------------------------------
// app mode (fp8, 32B aligned texels): lane sub owns 16 padded channels.
// One uint4 load per corner.
// ---------------------------------------------------------------------------
__device__ __forceinline__ void app_f8(const unsigned char* __restrict__ pl,
                                       const unsigned char* __restrict__ ln,
                                       const __half2* __restrict__ btR,
                                       const __half2* __restrict__ btG,
                                       const __half2* __restrict__ btB,
                                       int x0, int y0, int l0,
                                       __half2 W00, __half2 W01,
                                       __half2 W10, __half2 W11,
                                       __half2 wl, int sub,
                                       float& dr, float& dg, float& db) {
  const unsigned char* p = pl + ((size_t)(y0 * 256 + x0) << 5) + sub * 16;
  uint4 qA = *(const uint4*)p;
  uint4 qB = *(const uint4*)(p + 32);
  uint4 qC = *(const uint4*)(p + 8192);
  uint4 qD = *(const uint4*)(p + 8192 + 32);
  const unsigned char* lp = ln + (l0 << 5) + sub * 16;
  uint4 qLA = *(const uint4*)lp;
  uint4 qLB = *(const uint4*)(lp + 32);
  __half2 A[8], B[8], C[8], D[8], LA[8], LB[8];
  dec16f8(qA, A); dec16f8(qB, B); dec16f8(qC, C); dec16f8(qD, D);
  dec16f8(qLA, LA); dec16f8(qLB, LB);
#pragma unroll
  for (int r = 0; r < 8; ++r) {
    __half2 m = __hmul2(W00, A[r]);
    m = __hfma2(W01, B[r], m);
    m = __hfma2(W10, C[r], m);
    m = __hfma2(W11, D[r], m);
    __half2 l = lerp2(LA[r], LB[r], wl);
    __half2 av = __hmul2(m, l);
    dr = dot2acc(av, btR[r], dr);
    dg = dot2acc(av, btG[r], dg);
    db = dot2acc(av, btB[r], db);
  }
}

// ---------------------------------------------------------------------------
// Sample kernel: 2 lanes per sample; block = 128 samples of one ray.
// 8192 blocks x 256 threads.
// ---------------------------------------------------------------------------
__global__ __launch_bounds__(256) void sample_kernel(
    const float4* __restrict__ rd, const float* __restrict__ basis,
    const unsigned char* __restrict__ dpt, const __half* __restrict__ dlt,
    const unsigned char* __restrict__ apt, const unsigned char* __restrict__ alt,
    uint2* __restrict__ smp) {
  __shared__ __align__(16) __half bth[3][3][32];  // [k][mode][ch], pad zeroed
  int tid = threadIdx.x;
  // 288 entries > 256 threads: stride-loop (r5 bug: tail was uninitialized).
  for (int t = tid; t < 288; t += 256) {
    int k = t / 96, rem = t - k * 96;
    int m = rem >> 5, c = rem & 31;
    float v = (c < 24) ? basis[(m * 24 + c) * 3 + k] : 0.0f;
    bth[k][m][c] = __float2half(v);
  }
  __syncthreads();

  int ray = blockIdx.x >> 1;
  int j = ((blockIdx.x & 1) << 7) + (tid >> 1);
  int sub = tid & 1;

  float4 ra = rd[ray * 2];
  float4 rb = rd[ray * 2 + 1];
  float z = fmaf((float)j, rb.w, ra.w);
  float c0 = fmaf(rb.x, z, ra.x);
  float c1 = fmaf(rb.y, z, ra.y);
  float c2 = fmaf(rb.z, z, ra.z);
  bool inside = (fabsf(c0) <= 1.0f) && (fabsf(c1) <= 1.0f) && (fabsf(c2) <= 1.0f);

  float sig = 0.f, dr = 0.f, dg = 0.f, db = 0.f;
  if (inside) {
    int i0, i1, i2;
    float w0, w1, w2;
    grid_uv(c0, i0, w0);
    grid_uv(c1, i1, w1);
    grid_uv(c2, i2, w2);
    __half2 h0 = __float2half2_rn(w0);
    __half2 h1 = __float2half2_rn(w1);
    __half2 h2 = __float2half2_rn(w2);
    // MAT_MODE = [(0,1),(0,2),(1,2)], VEC_MODE = [2,1,0]
    __half2 Wa00, Wa01, Wa10, Wa11;  // mode 0: (w0,w1)
    __half2 Wb00, Wb01, Wb10, Wb11;  // mode 1: (w0,w2)
    __half2 Wc00, Wc01, Wc10, Wc11;  // mode 2: (w1,w2)
    bilin_w(w0, w1, Wa00, Wa01, Wa10, Wa11);
    bilin_w(w0, w2, Wb00, Wb01, Wb10, Wb11);
    bilin_w(w1, w2, Wc00, Wc01, Wc10, Wc11);

    sig = density_f8(dpt + 0 * 1048576, dlt + 0 * 4096, i0, i1, i2,
                     Wa00, Wa01, Wa10, Wa11, h2, sub, sig);
    sig = density_f8(dpt + 1 * 1048576, dlt + 1 * 4096, i0, i2, i1,
                     Wb00, Wb01, Wb10, Wb11, h1, sub, sig);
    sig = density_f8(dpt + 2 * 1048576, dlt + 2 * 4096, i1, i2, i0,
                     Wc00, Wc01, Wc10, Wc11, h0, sub, sig);
    app_f8(apt + 0 * 2097152, alt + 0 * 8192,
           (const __half2*)&bth[0][0][sub * 16], (const __half2*)&bth[1][0][sub * 16],
           (const __half2*)&bth[2][0][sub * 16], i0, i1, i2,
           Wa00, Wa01, Wa10, Wa11, h2, sub, dr, dg, db);
    app_f8(apt + 1 * 2097152, alt + 1 * 8192,
           (const __half2*)&bth[0][1][sub * 16], (const __half2*)&bth[1][1][sub * 16],
           (const __half2*)&bth[2][1][sub * 16], i0, i2, i1,
           Wb00, Wb01, Wb10, Wb11, h1, sub, dr, dg, db);
    app_f8(apt + 2 * 2097152, alt + 2 * 8192,
           (const __half2*)&bth[0][2][sub * 16], (const __half2*)&bth[1][2][sub * 16],
           (const __half2*)&bth[2][2][sub * 16], i1, i2, i0,
           Wc00, Wc01, Wc10, Wc11, h0, sub, dr, dg, db);
  }
  // reduce over the 2-lane group
  sig += __shfl_xor(sig, 1, 64);
  dr += __shfl_xor(dr, 1, 64);
  dg += __shfl_xor(dg, 1, 64);
  db += __shfl_xor(db, 1, 64);

  if (sub == 0) {
    // softplus via fast log/exp: sp = max(x,0) + log(1 + exp(-|x|))
    float e = __expf(-fabsf(sig));
    float sp = fmaxf(sig, 0.f) + __logf(1.0f + e);
    float alpha = inside ? (1.0f - __expf(-sp * rb.w)) : 0.0f;
    float cr = __builtin_amdgcn_rcpf(1.0f + __expf(-dr));
    float cg = __builtin_amdgcn_rcpf(1.0f + __expf(-dg));
    float cb = __builtin_amdgcn_rcpf(1.0f + __expf(-db));
    uint2 sv;
    sv.x = pack2h(alpha, cr);
    sv.y = pack2h(cg, cb);
    smp[ray * 256 + j] = sv;
  }
}

// ---------------------------------------------------------------------------
// Scan kernel: per-ray transmittance scan + composite. One wave per ray.
// ---------------------------------------------------------------------------
__global__ __launch_bounds__(256) void scan_kernel(
    const float4* __restrict__ rd, const uint2* __restrict__ smp,
    float* __restrict__ out) {
  int tid = threadIdx.x;
  int lane = tid & 63;
  int ray = blockIdx.x * 4 + (tid >> 6);

  float tmin = rd[ray * 2].w;
  float dt = rd[ray * 2 + 1].w;

  float C = 1.0f;
  float racc = 0.f, gacc = 0.f, bacc = 0.f, wsum = 0.f, dsum = 0.f;

  for (int q = 0; q < 4; ++q) {
    int j = q * 64 + lane;
    uint2 sv = smp[ray * 256 + j];
    float2 ar = __half22float2(__builtin_bit_cast(__half2, sv.x));
    float2 gb = __half22float2(__builtin_bit_cast(__half2, sv.y));
    float alpha = ar.x;
    float z = fmaf((float)j, dt, tmin);

    float p = 1.0f - alpha + 1e-10f;
#pragma unroll
    for (int off = 1; off < 64; off <<= 1) {
      float t = __shfl_up(p, off, 64);
      if (lane >= off) p *= t;
    }
    float tot = __shfl(p, 63, 64);
    float e = __shfl_up(p, 1, 64);
    if (lane == 0) e = 1.0f;
    float Tj = C * e;
    float w = alpha * Tj;
    racc += w * ar.y;
    gacc += w * gb.x;
    bacc += w * gb.y;
    wsum += w;
    dsum += w * z;
    C *= tot;
  }

#pragma unroll
  for (int off = 32; off > 0; off >>= 1) {
    racc += __shfl_down(racc, off, 64);
    gacc += __shfl_down(gacc, off, 64);
    bacc += __shfl_down(bacc, off, 64);
    wsum += __shfl_down(wsum, off, 64);
    dsum += __shfl_down(dsum, off, 64);
  }
  if (lane == 0) {
    float bgw = 1.0f - wsum;  // WHITE_BG
    out[ray * 3 + 0] = fminf(fmaxf(racc + bgw, 0.f), 1.f);
    out[ray * 3 + 1] = fminf(fmaxf(gacc + bgw, 0.f), 1.f);
    out[ray * 3 + 2] = fminf(fmaxf(bacc + bgw, 0.f), 1.f);
    out[NRAYS * 3 + ray] = dsum;
  }
}

// ---------------------------------------------------------------------------
// Fallback (ws too small): single-kernel fp32 render on original layout.
// ---------------------------------------------------------------------------
__device__ __forceinline__ float density_orig(const float* __restrict__ plane,
                                              const float* __restrict__ line,
                                              float cx, float cy, float cw) {
  int x0, y0, l0; float wx, wy, wl;
  grid_uv(cx, x0, wx); grid_uv(cy, y0, wy); grid_uv(cw, l0, wl);
  int base = y0 * 256 + x0;
  float s = 0.0f;
#pragma unroll 4
  for (int c = 0; c < 16; ++c) {
    const float* pc = plane + c * 65536;
    float v00 = pc[base], v01 = pc[base + 1];
    float v10 = pc[base + 256], v11 = pc[base + 257];
    float top = fmaf(wx, v01 - v00, v00);
    float bot = fmaf(wx, v11 - v10, v10);
    float mid = fmaf(wy, bot - top, top);
    float la = line[c * 256 + l0], lb = line[c * 256 + l0 + 1];
    float lv = fmaf(wl, lb - la, la);
    s += mid * lv;
  }
  return s;
}

__device__ __forceinline__ void app_orig(const float* __restrict__ plane,
                                         const float* __restrict__ line,
                                         const float* __restrict__ btR,
                                         const float* __restrict__ btG,
                                         const float* __restrict__ btB,
                                         float cx, float cy, float cw,
                                         float& dr, float& dg, float& db) {
  int x0, y0, l0; float wx, wy, wl;
  grid_uv(cx, x0, wx); grid_uv(cy, y0, wy); grid_uv(cw, l0, wl);
  int base = y0 * 256 + x0;
#pragma unroll 4
  for (int c = 0; c < 24; ++c) {
    const float* pc = plane + c * 65536;
    float v00 = pc[base], v01 = pc[base + 1];
    float v10 = pc[base + 256], v11 = pc[base + 257];
    float top = fmaf(wx, v01 - v00, v00);
    float bot = fmaf(wx, v11 - v10, v10);
    float mid = fmaf(wy, bot - top, top);
    float la = line[c * 256 + l0], lb = line[c * 256 + l0 + 1];
    float lv = fmaf(wl, lb - la, la);
    float av = mid * lv;
    dr += av * btR[c]; dg += av * btG[c]; db += av * btB[c];
  }
}

__global__ __launch_bounds__(256) void render_fallback(
    const float* __restrict__ rays, const float* __restrict__ basis,
    const float* __restrict__ aabb, const float* __restrict__ dplane,
    const float* __restrict__ dline, const float* __restrict__ aplane,
    const float* __restrict__ aline, float* __restrict__ out) {
  __shared__ float bt[3 * 72];
  int tid = threadIdx.x;
  if (tid < 216) {
    int k = tid / 72, r = tid - k * 72;
    bt[tid] = basis[r * 3 + k];
  }
  __syncthreads();
  int lane = tid & 63;
  int ray = blockIdx.x * 4 + (tid >> 6);

  float o0 = rays[ray * 6 + 0], o1 = rays[ray * 6 + 1], o2 = rays[ray * 6 + 2];
  float d0 = rays[ray * 6 + 3], d1 = rays[ray * 6 + 4], d2 = rays[ray * 6 + 5];
  float A0 = aabb[0], A1 = aabb[1], A2 = aabb[2];
  float B0 = aabb[3], B1 = aabb[4], B2 = aabb[5];
  float v0 = fabsf(d0) < 1e-6f ? 1e-6f : d0;
  float v1 = fabsf(d1) < 1e-6f ? 1e-6f : d1;
  float v2 = fabsf(d2) < 1e-6f ? 1e-6f : d2;
  float ra0 = (B0 - o0) / v0, rb0 = (A0 - o0) / v0;
  float ra1 = (B1 - o1) / v1, rb1 = (A1 - o1) / v1;
  float ra2 = (B2 - o2) / v2, rb2 = (A2 - o2) / v2;
  float tmin = fmaxf(fmaxf(fminf(ra0, rb0), fminf(ra1, rb1)), fminf(ra2, rb2));
  tmin = fmaxf(tmin, 0.05f);
  float tmax = fminf(fminf(fmaxf(ra0, rb0), fmaxf(ra1, rb1)), fmaxf(ra2, rb2));
  tmax = fmaxf(tmax, tmin + 0.001f);
  float dt = (tmax - tmin) * (1.0f / 255.0f);
  float s0 = 2.0f / (B0 - A0), s1 = 2.0f / (B1 - A1), s2 = 2.0f / (B2 - A2);

  float C = 1.0f;
  float racc = 0.f, gacc = 0.f, bacc = 0.f, wsum = 0.f, dsum = 0.f;
  for (int q = 0; q < 4; ++q) {
    int j = q * 64 + lane;
    float sfrac = (float)j * (1.0f / 255.0f);
    float z = tmin * (1.0f - sfrac) + tmax * sfrac;
    float c0 = (o0 + d0 * z - A0) * s0 - 1.0f;
    float c1 = (o1 + d1 * z - A1) * s1 - 1.0f;
    float c2 = (o2 + d2 * z - A2) * s2 - 1.0f;
    bool inside = (fabsf(c0) <= 1.0f) && (fabsf(c1) <= 1.0f) && (fabsf(c2) <= 1.0f);
    float alpha = 0.f, cr = 0.f, cg = 0.f, cb = 0.f;
    if (inside) {
      float sig = 0.f, dr = 0.f, dg = 0.f, db = 0.f;
      sig += density_orig(dplane + 0 * 1048576, dline + 0 * 4096, c0, c1, c2);
      sig += density_orig(dplane + 1 * 1048576, dline + 1 * 4096, c0, c2, c1);
      sig += density_orig(dplane + 2 * 1048576, dline + 2 * 4096, c1, c2, c0);
      app_orig(aplane + 0 * 1572864, aline + 0 * 6144,
               &bt[0 * 72 + 0], &bt[1 * 72 + 0], &bt[2 * 72 + 0],
               c0, c1, c2, dr, dg, db);
      app_orig(aplane + 1 * 1572864, aline + 1 * 6144,
               &bt[0 * 72 + 24], &bt[1 * 72 + 24], &bt[2 * 72 + 24],
               c0, c2, c1, dr, dg, db);
      app_orig(aplane + 2 * 1572864, aline + 2 * 6144,
               &bt[0 * 72 + 48], &bt[1 * 72 + 48], &bt[2 * 72 + 48],
               c1, c2, c0, dr, dg, db);
      float sp = fmaxf(sig, 0.f) + log1pf(expf(-fabsf(sig)));
      alpha = 1.0f - expf(-sp * dt);
      cr = 1.0f / (1.0f + expf(-dr));
      cg = 1.0f / (1.0f + expf(-dg));
      cb = 1.0f / (1.0f + expf(-db));
    }
    float p = 1.0f - alpha + 1e-10f;
#pragma unroll
    for (int off = 1; off < 64; off <<= 1) {
      float t = __shfl_up(p, off, 64);
      if (lane >= off) p *= t;
    }
    float tot = __shfl(p, 63, 64);
    float e = __shfl_up(p, 1, 64);
    if (lane == 0) e = 1.0f;
    float Tj = C * e;
    float w = alpha * Tj;
    racc += w * cr; gacc += w * cg; bacc += w * cb;
    wsum += w; dsum += w * z;
    C *= tot;
  }
#pragma unroll
  for (int off = 32; off > 0; off >>= 1) {
    racc += __shfl_down(racc, off, 64);
    gacc += __shfl_down(gacc, off, 64);
    bacc += __shfl_down(bacc, off, 64);
    wsum += __shfl_down(wsum, off, 64);
    dsum += __shfl_down(dsum, off, 64);
  }
  if (lane == 0) {
    float bgw = 1.0f - wsum;
    out[ray * 3 + 0] = fminf(fmaxf(racc + bgw, 0.f), 1.f);
    out[ray * 3 + 1] = fminf(fmaxf(gacc + bgw, 0.f), 1.f);
    out[ray * 3 + 2] = fminf(fmaxf(bacc + bgw, 0.f), 1.f);
    out[NRAYS * 3 + ray] = dsum;
  }
}

extern "C" void kernel_launch(void* const* d_in, const int* in_sizes, int n_in,
                              void* d_out, int out_size, void* d_ws, size_t ws_size,
                              hipStream_t stream) {
  const float* rays  = (const float*)d_in[0];
  const float* dp    = (const float*)d_in[1];
  const float* dl    = (const float*)d_in[2];
  const float* ap    = (const float*)d_in[3];
  const float* al    = (const float*)d_in[4];
  const float* basis = (const float*)d_in[5];
  const float* aabb  = (const float*)d_in[6];
  float* out = (float*)d_out;

  if (ws_size >= WS_NEED) {
    char* ws = (char*)d_ws;
    unsigned char* dpt = (unsigned char*)(ws + DPT_B);
    __half* dlt = (__half*)(ws + DLT_B);
    unsigned char* apt = (unsigned char*)(ws + APT_B);
    unsigned char* alt = (unsigned char*)(ws + ALT_B);
    uint2* smp = (uint2*)(ws + SMP_B);
    float4* rayd = (float4*)(ws + RAY_B);
    prep_kernel<<<1558, 256, 0, stream>>>(dp, ap, dl, al, rays, aabb,
                                          dpt, apt, dlt, alt, rayd);
    sample_kernel<<<NRAYS * 2, 256, 0, stream>>>(rayd, basis, dpt, dlt, apt, alt, smp);
    scan_kernel<<<NRAYS / 4, 256, 0, stream>>>(rayd, smp, out);
  } else {
    render_fallback<<<NRAYS / 4, 256, 0, stream>>>(
        rays, basis, aabb, dp, dl, ap, al, out);
  }
}